// Round 7
// baseline (225.804 us; speedup 1.0000x reference)
//
#include <hip/hip_runtime.h>
#include <hip/hip_bf16.h>

typedef __hip_bfloat16 bf16;
typedef short short8 __attribute__((ext_vector_type(8)));
typedef float floatx4 __attribute__((ext_vector_type(4)));

#define SZ (8192*192)   // one (B*L, C) fp32 plane in floats

__device__ __forceinline__ unsigned short f2b(float f) {
    unsigned u = __builtin_bit_cast(unsigned, f);
    u += 0x7FFFu + ((u >> 16) & 1u);   // RNE
    return (unsigned short)(u >> 16);
}
__device__ __forceinline__ float b2f(unsigned short h) {
    unsigned u = ((unsigned)h) << 16;
    return __builtin_bit_cast(float, u);
}
__device__ __forceinline__ unsigned pk2(float a, float b) {
    // packed bf16 pair (a in low half / lower address)
    return ((unsigned)f2b(b) << 16) | (unsigned)f2b(a);
}

// ---------------- dtype detect: bf16 vs fp32 inputs ----------------
__global__ void detect_kernel(const unsigned short* __restrict__ x16, int* __restrict__ flag) {
    __shared__ int cnt;
    if (threadIdx.x == 0) cnt = 0;
    __syncthreads();
    int c = 0;
    for (int i = threadIdx.x; i < 8192; i += 256) {
        int e = (x16[i] >> 7) & 0xFF;
        if (e >= 152) c++;
    }
    if (c) atomicAdd(&cnt, c);
    __syncthreads();
    if (threadIdx.x == 0) *flag = (cnt >= 32) ? 1 : 0;
}

// ---------------- fused weight transpose (->bf16 NxK) + small-vector cvt (->f32) ----------------
struct WPA { const void* s[11]; };
// s[]: w_qkv, w_proj, w_fc1, w_fc2, b_proj, g1, b1, g2, b2, b_fc1, b_fc2

__global__ __launch_bounds__(256) void wprep_kernel(WPA a, unsigned short* __restrict__ wdst,
                                                    float* __restrict__ vdst,
                                                    const int* __restrict__ flag) {
    int i = blockIdx.x * 256 + threadIdx.x;
    int f = *flag;
    if (i < 442368) {
        int seg, base, K, N;
        if (i < 110592)      { seg = 0; base = 0;      K = 192; N = 576; }
        else if (i < 147456) { seg = 1; base = 110592; K = 192; N = 192; }
        else if (i < 294912) { seg = 2; base = 147456; K = 192; N = 768; }
        else                 { seg = 3; base = 294912; K = 768; N = 192; }
        int j = i - base;
        int n = j / K, k = j - n * K;
        size_t src = (size_t)k * N + n;
        float v = f ? ((const float*)a.s[seg])[src] : b2f(((const unsigned short*)a.s[seg])[src]);
        wdst[i] = f2b(v);
    } else if (i < 444288) {
        int j = i - 442368;
        int seg, off;
        if (j < 960)       { seg = 4 + j / 192; off = j % 192; }
        else if (j < 1728) { seg = 9; off = j - 960; }
        else               { seg = 10; off = j - 1728; }
        float v = f ? ((const float*)a.s[seg])[off] : b2f(((const unsigned short*)a.s[seg])[off]);
        vdst[j] = v;
    }
}

// ---------------- prep: x (B,C,4096) -> xt=2x (B*L,C) f32 and img=LN bf16 ----------------
__global__ __launch_bounds__(256) void prep_kernel(const void* __restrict__ xin,
        const int* __restrict__ flag,
        const float* __restrict__ g1, const float* __restrict__ b1,
        float* __restrict__ xt, unsigned short* __restrict__ img) {
    __shared__ float tile[192][33];
    __shared__ float mu[32], rs[32];
    int tid = threadIdx.x;
    int t0 = blockIdx.x * 32;
    int b = t0 >> 12;
    int ts = t0 & 4095;
    int f = *flag;
    for (int idx = tid; idx < 192 * 32; idx += 256) {
        int c = idx >> 5, tt = idx & 31;
        int gi = ((b * 192 + c) << 12) + ts + tt;
        float raw = f ? ((const float*)xin)[gi] : b2f(((const unsigned short*)xin)[gi]);
        tile[c][tt] = 2.0f * raw;
    }
    __syncthreads();
    {
        // 8 threads per token, 24 channels each, then 3-step shfl reduce within the 8-lane group
        int tt = tid >> 3, j = tid & 7;
        int c0 = j * 24;
        float s = 0.f, sq = 0.f;
        #pragma unroll
        for (int i = 0; i < 24; ++i) { float v = tile[c0 + i][tt]; s += v; sq += v * v; }
        s += __shfl_xor(s, 1); sq += __shfl_xor(sq, 1);
        s += __shfl_xor(s, 2); sq += __shfl_xor(sq, 2);
        s += __shfl_xor(s, 4); sq += __shfl_xor(sq, 4);
        if (j == 0) {
            float m = s * (1.0f / 192.0f);
            float var = sq * (1.0f / 192.0f) - m * m;
            mu[tt] = m;
            rs[tt] = rsqrtf(var + 1e-5f);
        }
    }
    __syncthreads();
    for (int idx = tid; idx < 32 * 192; idx += 256) {
        int tt = idx / 192, c = idx % 192;
        float v = tile[c][tt];
        int o = (t0 + tt) * 192 + c;
        xt[o] = v;
        img[o] = f2b((v - mu[tt]) * rs[tt] * g1[c] + b1[c]);
    }
}

// window-position index of token t (within batch) for branch br: g = wb*1024 + q.
// Inverse of tok_of. 4 consecutive tokens (t 4-aligned) -> 4 consecutive g.
__device__ __forceinline__ int g_of(int br, int t) {
    if (br == 0) return (((t >> 2) & 3) << 10) | ((t >> 8) << 6) | (((t >> 4) & 15) << 2) | (t & 3);
    if (br == 1) return (((t >> 6) & 3) << 10) | ((t >> 8) << 6) | (((t >> 4) & 3) << 4) | (t & 15);
    return t;
}

// ---------------- MFMA GEMM, per-wave 32x64 tile (FH=2), W waves/block ----------------
// MODE 0: out bf16 = acc; q-cols (<192) pre-scaled by 1/sqrt(32); V-cols (>=384)
//         written TRANSPOSED+PERMUTED to vt[b][br*2+head][d][gperm] matching P's key
//         ordering (pos = 4*(key&15) + (key>>4) within each 64-key chunk)      (qkv)
// MODE 1: out f32  = acc + bias + resid                            (proj)
// MODE 2: out bf16 = gelu(acc + bias)                              (fc1)
// MODE 3: out f32  = acc + bias + resid (in-place resid==out ok)   (fc2)
template <int MODE, int W>
__global__ __launch_bounds__(64 * W) void mfma_gemm(const unsigned short* __restrict__ A,
        const unsigned short* __restrict__ WT, const float* __restrict__ bias,
        const float* __restrict__ resid, void* __restrict__ out,
        unsigned short* __restrict__ vt, int N, int K) {
    int wave = threadIdx.x >> 6, lane = threadIdx.x & 63;
    int quad = lane >> 4, l16 = lane & 15;
    int m0 = blockIdx.x * (32 * W) + wave * 32, n0 = blockIdx.y * 64;
    const unsigned short* ap = A + (size_t)(m0 + l16) * K + quad * 8;
    const unsigned short* wp = WT + (size_t)(n0 + l16) * K + quad * 8;
    floatx4 acc[2][4] = {};
    #pragma unroll 2
    for (int kc = 0; kc < K; kc += 32) {
        short8 a0 = *reinterpret_cast<const short8*>(ap + kc);
        short8 a1 = *reinterpret_cast<const short8*>(ap + (size_t)16 * K + kc);
        #pragma unroll
        for (int nt = 0; nt < 4; ++nt) {
            short8 w = *reinterpret_cast<const short8*>(wp + (size_t)nt * 16 * K + kc);
            acc[0][nt] = __builtin_amdgcn_mfma_f32_16x16x32_bf16(a0, w, acc[0][nt], 0, 0, 0);
            acc[1][nt] = __builtin_amdgcn_mfma_f32_16x16x32_bf16(a1, w, acc[1][nt], 0, 0, 0);
        }
    }
    #pragma unroll
    for (int fh = 0; fh < 2; ++fh) {
        #pragma unroll
        for (int nt = 0; nt < 4; ++nt) {
            int col = n0 + nt * 16 + l16;
            if (MODE == 0 && n0 >= 384) {
                // V columns: transposed into vt (bf16), PERMUTED key order within chunk.
                // tokens tl..tl+3 -> g0..g0+3 (g0 4-aligned) -> positions pp+4r.
                int cv = col - 384;               // br*64 + head*32 + d
                int row0 = m0 + fh * 16 + quad * 4;
                int bb_ = row0 >> 12, tl = row0 & 4095;
                int g0 = g_of(cv >> 6, tl);
                int pp = (g0 & ~63) + 4 * (g0 & 15) + ((g0 >> 4) & 3);
                unsigned short* vrow = vt + ((size_t)((bb_ * 6 + (cv >> 5)) * 32 + (cv & 31)) << 12);
                vrow[pp]      = f2b(acc[fh][nt][0]);
                vrow[pp + 4]  = f2b(acc[fh][nt][1]);
                vrow[pp + 8]  = f2b(acc[fh][nt][2]);
                vrow[pp + 12] = f2b(acc[fh][nt][3]);
            } else {
                #pragma unroll
                for (int r = 0; r < 4; ++r) {
                    int row = m0 + fh * 16 + quad * 4 + r;
                    float v = acc[fh][nt][r];
                    if (MODE == 0 && col < 192) v *= 0.17677669529663689f;
                    if (MODE >= 1) v += bias[col];
                    if (MODE == 2) v = 0.5f * v * (1.0f + erff(v * 0.70710678118654752f));
                    size_t o = (size_t)row * N + col;
                    if (MODE == 0 || MODE == 2) ((unsigned short*)out)[o] = f2b(v);
                    else                        ((float*)out)[o] = v + resid[o];
                }
            }
        }
    }
}

// ---------------- MFMA windowed attention (no-max softmax, permuted key axis) ----------------
// window shapes: br0=(16,16,4), br1=(16,4,16), br2=(4,16,16); S=1024, hd=32
__device__ __forceinline__ int tok_of(int br, int wb, int q) {
    if (br == 0) return ((q >> 6) << 8) | (((q >> 2) & 15) << 4) | (wb << 2) | (q & 3);
    else if (br == 1) return ((q >> 6) << 8) | (((wb << 2) + ((q >> 4) & 3)) << 4) | (q & 15);
    else return (((wb << 2) + (q >> 8)) << 8) | (q & 255);
}

// SPLIT=1: full 16 kt tiles per block, normalize + write attb bf16 (grid 768)
// SPLIT=2: 8 kt tiles per block, write f32 partial O (po) + partial denom (pl) (grid 1536)
// BARRIER-FREE + PIPELINED: V B-fragments come directly from the pre-transposed+permuted
// vt buffer; next iteration's K/V fragments are prefetched into registers while the
// current iteration computes (QK + exp + P-write + PV hide the ~200-900cy load latency).
// P is per-wave LDS (same-wave write->read ordered by lgkmcnt, no __syncthreads).
template <int SPLIT>
__global__ __launch_bounds__(256) void attn_mfma(const unsigned short* __restrict__ qkv,
        const unsigned short* __restrict__ vt,
        unsigned short* __restrict__ attb, float* __restrict__ po, float* __restrict__ pl) {
    __shared__ __align__(16) unsigned short P[4][16 * 72];   // per-wave, rows=q, cols=pos(k)
    const int chunk = 96 * SPLIT;  // (768*SPLIT)/8, grid % 8 == 0 -> bijective
    int hw = blockIdx.x;
    int bid = (hw & 7) * chunk + (hw >> 3);
    int kh, rest;
    if (SPLIT == 2) { kh = bid & 1; rest = bid >> 1; }
    else            { kh = 0;       rest = bid; }
    int qt = rest & 15, head = (rest >> 4) & 1, wb = (rest >> 5) & 3, b = (rest >> 7) & 1, br = rest >> 8;
    int tid = threadIdx.x;
    int wave = tid >> 6, lane = tid & 63, quad = lane >> 4, l16 = lane & 15;
    int coff = br * 64 + head * 32;
    int tb = b << 12;
    // Q a-frag (q pre-scaled in qkv GEMM epilogue)
    int tq = tok_of(br, wb, qt * 64 + wave * 16 + l16);
    short8 aq = *reinterpret_cast<const short8*>(qkv + (size_t)(tb + tq) * 576 + coff + quad * 8);
    floatx4 o0 = {}, o1 = {};
    float lsum[4] = {0.f, 0.f, 0.f, 0.f};
    unsigned short* Pw = P[wave];

    const int NT = 16 / SPLIT;
    const int kc0 = kh * NT * 64;
    const size_t stp = (size_t)((br == 2) ? 64 : 256) * 576;  // K token step per kt

    // K fragment pointers (affine in kt -> pointer-stepped)
    const unsigned short* kpA = qkv + (size_t)(tb + tok_of(br, wb, kc0 + l16))      * 576 + 192 + coff + quad * 8;
    const unsigned short* kpB = qkv + (size_t)(tb + tok_of(br, wb, kc0 + 16 + l16)) * 576 + 192 + coff + quad * 8;
    const unsigned short* kpC = qkv + (size_t)(tb + tok_of(br, wb, kc0 + 32 + l16)) * 576 + 192 + coff + quad * 8;
    const unsigned short* kpD = qkv + (size_t)(tb + tok_of(br, wb, kc0 + 48 + l16)) * 576 + 192 + coff + quad * 8;
    // V^T fragment pointers into vt: rows d = l16 / l16+16, cols = permuted pos (step 64/iter)
    const unsigned short* vsl = vt + ((size_t)((b * 6 + br * 2 + head) * 32) << 12) + (wb << 10) + kc0 + quad * 8;
    const unsigned short* v0p = vsl + ((size_t)l16 << 12);
    const unsigned short* v1p = vsl + ((size_t)(l16 + 16) << 12);

    // prefetch iteration 0's fragments
    short8 k0 = *reinterpret_cast<const short8*>(kpA);
    short8 k1 = *reinterpret_cast<const short8*>(kpB);
    short8 k2 = *reinterpret_cast<const short8*>(kpC);
    short8 k3 = *reinterpret_cast<const short8*>(kpD);
    short8 vb00 = *reinterpret_cast<const short8*>(v0p);
    short8 vb01 = *reinterpret_cast<const short8*>(v0p + 32);
    short8 vb10 = *reinterpret_cast<const short8*>(v1p);
    short8 vb11 = *reinterpret_cast<const short8*>(v1p + 32);

    for (int it = 0; it < NT; ++it) {
        short8 ck0 = k0, ck1 = k1, ck2 = k2, ck3 = k3;
        short8 cv00 = vb00, cv01 = vb01, cv10 = vb10, cv11 = vb11;
        // issue next iteration's global loads now; their latency hides under
        // QK + exp + P-write + PV of the current iteration
        if (it + 1 < NT) {
            kpA += stp; kpB += stp; kpC += stp; kpD += stp;
            v0p += 64; v1p += 64;
            k0 = *reinterpret_cast<const short8*>(kpA);
            k1 = *reinterpret_cast<const short8*>(kpB);
            k2 = *reinterpret_cast<const short8*>(kpC);
            k3 = *reinterpret_cast<const short8*>(kpD);
            vb00 = *reinterpret_cast<const short8*>(v0p);
            vb01 = *reinterpret_cast<const short8*>(v0p + 32);
            vb10 = *reinterpret_cast<const short8*>(v1p);
            vb11 = *reinterpret_cast<const short8*>(v1p + 32);
        }
        // S = Q K^T (4 tiles of 16 keys)
        floatx4 z = {};
        floatx4 s0 = __builtin_amdgcn_mfma_f32_16x16x32_bf16(aq, ck0, z, 0, 0, 0);
        floatx4 s1 = __builtin_amdgcn_mfma_f32_16x16x32_bf16(aq, ck1, z, 0, 0, 0);
        floatx4 s2 = __builtin_amdgcn_mfma_f32_16x16x32_bf16(aq, ck2, z, 0, 0, 0);
        floatx4 s3 = __builtin_amdgcn_mfma_f32_16x16x32_bf16(aq, ck3, z, 0, 0, 0);
        // exp (no max subtraction: |s|≲8 with LN'd inputs), P write as packed b64
        // P position of key c*16+l16 is 4*l16+c (same permutation as vt columns)
        #pragma unroll
        for (int r = 0; r < 4; ++r) {
            float p0 = __expf(s0[r]);
            float p1 = __expf(s1[r]);
            float p2 = __expf(s2[r]);
            float p3 = __expf(s3[r]);
            lsum[r] += (p0 + p1) + (p2 + p3);
            uint2 w2; w2.x = pk2(p0, p1); w2.y = pk2(p2, p3);
            *reinterpret_cast<uint2*>(Pw + (quad * 4 + r) * 72 + 4 * l16) = w2;
        }
        // O += P V (per-wave P from LDS, V from prefetched registers)
        const unsigned short* pr = Pw + l16 * 72;
        short8 a0 = *reinterpret_cast<const short8*>(pr + quad * 8);
        short8 a1 = *reinterpret_cast<const short8*>(pr + 32 + quad * 8);
        o0 = __builtin_amdgcn_mfma_f32_16x16x32_bf16(a0, cv00, o0, 0, 0, 0);
        o0 = __builtin_amdgcn_mfma_f32_16x16x32_bf16(a1, cv01, o0, 0, 0, 0);
        o1 = __builtin_amdgcn_mfma_f32_16x16x32_bf16(a0, cv10, o1, 0, 0, 0);
        o1 = __builtin_amdgcn_mfma_f32_16x16x32_bf16(a1, cv11, o1, 0, 0, 0);
    }
    // reduce softmax denominators within 16-lane groups
    #pragma unroll
    for (int r = 0; r < 4; ++r) {
        float ls = lsum[r];
        ls += __shfl_xor(ls, 1);
        ls += __shfl_xor(ls, 2);
        ls += __shfl_xor(ls, 4);
        ls += __shfl_xor(ls, 8);
        lsum[r] = ls;
    }
    if (SPLIT == 2) {
        // write f32 partials: O-half and denom-half are purely additive (no-max softmax)
        #pragma unroll
        for (int r = 0; r < 4; ++r) {
            int q = qt * 64 + wave * 16 + quad * 4 + r;
            int t = tok_of(br, wb, q);
            size_t o = ((size_t)(kh << 13) + tb + t) * 192 + coff;
            po[o + l16]      = o0[r];
            po[o + 16 + l16] = o1[r];
            if (l16 == 0) pl[(size_t)((kh << 13) + tb + t) * 6 + br * 2 + head] = lsum[r];
        }
    } else {
        #pragma unroll
        for (int r = 0; r < 4; ++r) {
            float inv = 1.0f / lsum[r];
            int q = qt * 64 + wave * 16 + quad * 4 + r;
            int t = tok_of(br, wb, q);
            size_t o = (size_t)(tb + t) * 192 + coff;
            attb[o + l16]      = f2b(o0[r] * inv);
            attb[o + 16 + l16] = f2b(o1[r] * inv);
        }
    }
}

// combine split-K halves: attb = (po0 + po1) / (pl0 + pl1), bf16
__global__ __launch_bounds__(256) void attn_combine(const float* __restrict__ po,
        const float* __restrict__ pl, unsigned short* __restrict__ attb) {
    int token = (blockIdx.x << 2) + (threadIdx.x >> 6);
    int lane = threadIdx.x & 63;
    const float* r0 = po + (size_t)token * 192;
    const float* r1 = r0 + (size_t)8192 * 192;
    const float* q0 = pl + (size_t)token * 6;
    const float* q1 = q0 + (size_t)8192 * 6;
    unsigned short* orow = attb + (size_t)token * 192;
    #pragma unroll
    for (int sgm = 0; sgm < 3; ++sgm) {
        int d = lane + sgm * 64;
        int g = d >> 5;                       // br*2 + head
        float denom = q0[g] + q1[g];
        orow[d] = f2b((r0[d] + r1[d]) / denom);
    }
}

// ---------------- LN over rows of (B*L, 192): f32 in -> bf16 out ----------------
__global__ __launch_bounds__(256) void ln_kernel(const float* __restrict__ in,
        const float* __restrict__ g, const float* __restrict__ bb, unsigned short* __restrict__ out) {
    int token = (blockIdx.x << 2) + (threadIdx.x >> 6);
    int lane = threadIdx.x & 63;
    const float* row = in + (size_t)token * 192;
    float v0 = row[lane], v1 = row[lane + 64], v2 = row[lane + 128];
    float s = v0 + v1 + v2, sq = v0 * v0 + v1 * v1 + v2 * v2;
    #pragma unroll
    for (int mask = 1; mask < 64; mask <<= 1) {
        s += __shfl_xor(s, mask);
        sq += __shfl_xor(sq, mask);
    }
    float m = s * (1.f / 192.f);
    float var = sq * (1.f / 192.f) - m * m;
    float rsd = rsqrtf(var + 1e-5f);
    unsigned short* orow = out + (size_t)token * 192;
    orow[lane]       = f2b((v0 - m) * rsd * g[lane]       + bb[lane]);
    orow[lane + 64]  = f2b((v1 - m) * rsd * g[lane + 64]  + bb[lane + 64]);
    orow[lane + 128] = f2b((v2 - m) * rsd * g[lane + 128] + bb[lane + 128]);
}

// ---------------- final transpose (B*L,C) f32 -> (B,C,4096) out dtype per flag ----------------
__global__ __launch_bounds__(256) void unprep_kernel(const float* __restrict__ xs,
                                                     void* __restrict__ out,
                                                     const int* __restrict__ flag) {
    __shared__ float tile[192][33];
    int tid = threadIdx.x;
    int t0 = blockIdx.x * 32;
    int b = t0 >> 12, ts = t0 & 4095;
    for (int idx = tid; idx < 32 * 192; idx += 256) {
        int tt = idx / 192, c = idx % 192;
        tile[c][tt] = xs[(size_t)(t0 + tt) * 192 + c];
    }
    __syncthreads();
    int f = *flag;
    for (int idx = tid; idx < 192 * 32; idx += 256) {
        int c = idx >> 5, tt = idx & 31;
        float v = tile[c][tt];
        int o = ((b * 192 + c) << 12) + ts + tt;
        if (f) ((float*)out)[o] = v;
        else   ((unsigned short*)out)[o] = f2b(v);
    }
}

extern "C" void kernel_launch(void* const* d_in, const int* in_sizes, int n_in,
                              void* d_out, int out_size, void* d_ws, size_t ws_size,
                              hipStream_t stream) {
    float* ws = (float*)d_ws;

    // small fp32 vectors: b_proj, g1, b1, g2, b2, b_fc1, b_fc2 (1920 floats)
    float* vbase = ws;
    float* bprojf = vbase + 0;
    float* g1f    = vbase + 192;
    float* b1f    = vbase + 384;
    float* g2f    = vbase + 576;
    float* b2f    = vbase + 768;
    float* bfc1f  = vbase + 960;
    float* bfc2f  = vbase + 1728;

    // transposed bf16 weights (N x K), 442368 ushorts
    unsigned short* wbase = (unsigned short*)(ws + 1920);
    unsigned short* wqkvT = wbase + 0;
    unsigned short* wprojT = wbase + 110592;
    unsigned short* wfc1T = wbase + 147456;
    unsigned short* wfc2T = wbase + 294912;

    size_t p = 1920 + 442368 / 2;           // float offset after weights
    float* xt = ws + p; p += SZ;            // fp32 residual stream (xs)
    unsigned short* img = (unsigned short*)(ws + p); p += SZ / 2;   // bf16; also lnb
    size_t pQ = p;
    unsigned short* qkv = (unsigned short*)(ws + pQ);               // bf16 8192x576
    unsigned short* hbuf = (unsigned short*)(ws + pQ);              // bf16 8192x768 (aliases qkv)
    p = pQ + 8192 * 768 / 2;
    unsigned short* attb = (unsigned short*)(ws + p); p += SZ / 2;  // bf16
    int* flag = (int*)(ws + p); p += 16;
    // pre-transposed V: vt[b][br*2+head][d=32][gperm=4096] bf16 (written by qkv GEMM epilogue)
    unsigned short* vtb = (unsigned short*)(ws + p); p += SZ / 2;
    // split-K attention partials (f32): 2 halves x (8192 x 192) O + (8192 x 6) denom
    float* po = ws + p; p += (size_t)2 * 8192 * 192;
    float* pl = ws + p; p += (size_t)2 * 8192 * 6;
    bool split_ok = ws_size >= p * sizeof(float);
    float* xs = xt;
    unsigned short* lnb = img;

    WPA wa;
    wa.s[0] = d_in[1];  wa.s[1] = d_in[2];  wa.s[2] = d_in[8];  wa.s[3] = d_in[10];
    wa.s[4] = d_in[3];  wa.s[5] = d_in[4];  wa.s[6] = d_in[5];  wa.s[7] = d_in[6];
    wa.s[8] = d_in[7];  wa.s[9] = d_in[9];  wa.s[10] = d_in[11];

    detect_kernel<<<dim3(1), dim3(256), 0, stream>>>((const unsigned short*)d_in[0], flag);
    wprep_kernel<<<dim3(1736), dim3(256), 0, stream>>>(wa, wbase, vbase, flag);
    prep_kernel<<<dim3(256), dim3(256), 0, stream>>>(d_in[0], flag, g1f, b1f, xt, img);
    // qkv: 2-wave blocks (1152 blocks); V columns go transposed+permuted into vtb
    mfma_gemm<0, 2><<<dim3(128, 9), dim3(128), 0, stream>>>(
        img, wqkvT, nullptr, nullptr, qkv, vtb, 576, 192);
    if (split_ok) {
        attn_mfma<2><<<dim3(1536), dim3(256), 0, stream>>>(qkv, vtb, nullptr, po, pl);
        attn_combine<<<dim3(2048), dim3(256), 0, stream>>>(po, pl, attb);
    } else {
        attn_mfma<1><<<dim3(768), dim3(256), 0, stream>>>(qkv, vtb, attb, nullptr, nullptr);
    }
    // proj: 1-wave blocks (768 blocks, 3/CU — every CU busy)
    mfma_gemm<1, 1><<<dim3(256, 3), dim3(64), 0, stream>>>(
        attb, wprojT, bprojf, xt, xs, nullptr, 192, 192);
    ln_kernel<<<dim3(2048), dim3(256), 0, stream>>>(xs, g2f, b2f, lnb);
    // fc1: 2-wave blocks (1536 blocks, 6/CU)
    mfma_gemm<2, 2><<<dim3(128, 12), dim3(128), 0, stream>>>(
        lnb, wfc1T, bfc1f, nullptr, hbuf, nullptr, 768, 192);
    // fc2: 1-wave blocks (768 blocks, 3/CU)
    mfma_gemm<3, 1><<<dim3(256, 3), dim3(64), 0, stream>>>(
        hbuf, wfc2T, bfc2f, xs, xs, nullptr, 192, 768);
    unprep_kernel<<<dim3(256), dim3(256), 0, stream>>>(xs, d_out, flag);
}

// Round 8
// 221.072 us; speedup vs baseline: 1.0214x; 1.0214x over previous
//
#include <hip/hip_runtime.h>
#include <hip/hip_bf16.h>

typedef __hip_bfloat16 bf16;
typedef short short8 __attribute__((ext_vector_type(8)));
typedef float floatx4 __attribute__((ext_vector_type(4)));

#define SZ (8192*192)   // one (B*L, C) fp32 plane in floats

__device__ __forceinline__ unsigned short f2b(float f) {
    unsigned u = __builtin_bit_cast(unsigned, f);
    u += 0x7FFFu + ((u >> 16) & 1u);   // RNE
    return (unsigned short)(u >> 16);
}
__device__ __forceinline__ float b2f(unsigned short h) {
    unsigned u = ((unsigned)h) << 16;
    return __builtin_bit_cast(float, u);
}
__device__ __forceinline__ unsigned pk2(float a, float b) {
    // packed bf16 pair (a in low half / lower address)
    return ((unsigned)f2b(b) << 16) | (unsigned)f2b(a);
}

// ---------------- dtype detect: bf16 vs fp32 inputs ----------------
__global__ void detect_kernel(const unsigned short* __restrict__ x16, int* __restrict__ flag) {
    __shared__ int cnt;
    if (threadIdx.x == 0) cnt = 0;
    __syncthreads();
    int c = 0;
    for (int i = threadIdx.x; i < 8192; i += 256) {
        int e = (x16[i] >> 7) & 0xFF;
        if (e >= 152) c++;
    }
    if (c) atomicAdd(&cnt, c);
    __syncthreads();
    if (threadIdx.x == 0) *flag = (cnt >= 32) ? 1 : 0;
}

// ---------------- fused weight transpose (->bf16 NxK) + small-vector cvt (->f32) ----------------
struct WPA { const void* s[11]; };
// s[]: w_qkv, w_proj, w_fc1, w_fc2, b_proj, g1, b1, g2, b2, b_fc1, b_fc2

__global__ __launch_bounds__(256) void wprep_kernel(WPA a, unsigned short* __restrict__ wdst,
                                                    float* __restrict__ vdst,
                                                    const int* __restrict__ flag) {
    int i = blockIdx.x * 256 + threadIdx.x;
    int f = *flag;
    if (i < 442368) {
        int seg, base, K, N;
        if (i < 110592)      { seg = 0; base = 0;      K = 192; N = 576; }
        else if (i < 147456) { seg = 1; base = 110592; K = 192; N = 192; }
        else if (i < 294912) { seg = 2; base = 147456; K = 192; N = 768; }
        else                 { seg = 3; base = 294912; K = 768; N = 192; }
        int j = i - base;
        int n = j / K, k = j - n * K;
        size_t src = (size_t)k * N + n;
        float v = f ? ((const float*)a.s[seg])[src] : b2f(((const unsigned short*)a.s[seg])[src]);
        wdst[i] = f2b(v);
    } else if (i < 444288) {
        int j = i - 442368;
        int seg, off;
        if (j < 960)       { seg = 4 + j / 192; off = j % 192; }
        else if (j < 1728) { seg = 9; off = j - 960; }
        else               { seg = 10; off = j - 1728; }
        float v = f ? ((const float*)a.s[seg])[off] : b2f(((const unsigned short*)a.s[seg])[off]);
        vdst[j] = v;
    }
}

// ---------------- prep: x (B,C,4096) -> xt=2x (B*L,C) f32 and img=LN bf16 ----------------
__global__ __launch_bounds__(256) void prep_kernel(const void* __restrict__ xin,
        const int* __restrict__ flag,
        const float* __restrict__ g1, const float* __restrict__ b1,
        float* __restrict__ xt, unsigned short* __restrict__ img) {
    __shared__ float tile[192][33];
    __shared__ float mu[32], rs[32];
    int tid = threadIdx.x;
    int t0 = blockIdx.x * 32;
    int b = t0 >> 12;
    int ts = t0 & 4095;
    int f = *flag;
    for (int idx = tid; idx < 192 * 32; idx += 256) {
        int c = idx >> 5, tt = idx & 31;
        int gi = ((b * 192 + c) << 12) + ts + tt;
        float raw = f ? ((const float*)xin)[gi] : b2f(((const unsigned short*)xin)[gi]);
        tile[c][tt] = 2.0f * raw;
    }
    __syncthreads();
    {
        // 8 threads per token, 24 channels each, then 3-step shfl reduce within the 8-lane group
        int tt = tid >> 3, j = tid & 7;
        int c0 = j * 24;
        float s = 0.f, sq = 0.f;
        #pragma unroll
        for (int i = 0; i < 24; ++i) { float v = tile[c0 + i][tt]; s += v; sq += v * v; }
        s += __shfl_xor(s, 1); sq += __shfl_xor(sq, 1);
        s += __shfl_xor(s, 2); sq += __shfl_xor(sq, 2);
        s += __shfl_xor(s, 4); sq += __shfl_xor(sq, 4);
        if (j == 0) {
            float m = s * (1.0f / 192.0f);
            float var = sq * (1.0f / 192.0f) - m * m;
            mu[tt] = m;
            rs[tt] = rsqrtf(var + 1e-5f);
        }
    }
    __syncthreads();
    for (int idx = tid; idx < 32 * 192; idx += 256) {
        int tt = idx / 192, c = idx % 192;
        float v = tile[c][tt];
        int o = (t0 + tt) * 192 + c;
        xt[o] = v;
        img[o] = f2b((v - mu[tt]) * rs[tt] * g1[c] + b1[c]);
    }
}

// window-position index of token t (within batch) for branch br: g = wb*1024 + q.
// Inverse of tok_of. 4 consecutive tokens (t 4-aligned) -> 4 consecutive g.
__device__ __forceinline__ int g_of(int br, int t) {
    if (br == 0) return (((t >> 2) & 3) << 10) | ((t >> 8) << 6) | (((t >> 4) & 15) << 2) | (t & 3);
    if (br == 1) return (((t >> 6) & 3) << 10) | ((t >> 8) << 6) | (((t >> 4) & 3) << 4) | (t & 15);
    return t;
}

// ---------------- MFMA GEMM, per-wave 32x64 tile (FH=2), W waves/block ----------------
// MODE 0: out bf16 = acc; q-cols (<192) pre-scaled by 1/sqrt(32); V-cols (>=384)
//         written TRANSPOSED+PERMUTED to vt[b][br*2+head][d][pos] where within each
//         64-key chunk pos(key) = (c>>1)*32 + (m>>2)*8 + (c&1)*4 + (m&3), c=key>>4,
//         m=key&15 — the in-register P layout of the swapped-QK attention.       (qkv)
// MODE 1: out f32  = acc + bias + resid                            (proj)
// MODE 2: out bf16 = gelu(acc + bias)                              (fc1)
// MODE 3: out f32  = acc + bias + resid (in-place resid==out ok)   (fc2)
template <int MODE, int W>
__global__ __launch_bounds__(64 * W) void mfma_gemm(const unsigned short* __restrict__ A,
        const unsigned short* __restrict__ WT, const float* __restrict__ bias,
        const float* __restrict__ resid, void* __restrict__ out,
        unsigned short* __restrict__ vt, int N, int K) {
    int wave = threadIdx.x >> 6, lane = threadIdx.x & 63;
    int quad = lane >> 4, l16 = lane & 15;
    int m0 = blockIdx.x * (32 * W) + wave * 32, n0 = blockIdx.y * 64;
    const unsigned short* ap = A + (size_t)(m0 + l16) * K + quad * 8;
    const unsigned short* wp = WT + (size_t)(n0 + l16) * K + quad * 8;
    floatx4 acc[2][4] = {};
    #pragma unroll 2
    for (int kc = 0; kc < K; kc += 32) {
        short8 a0 = *reinterpret_cast<const short8*>(ap + kc);
        short8 a1 = *reinterpret_cast<const short8*>(ap + (size_t)16 * K + kc);
        #pragma unroll
        for (int nt = 0; nt < 4; ++nt) {
            short8 w = *reinterpret_cast<const short8*>(wp + (size_t)nt * 16 * K + kc);
            acc[0][nt] = __builtin_amdgcn_mfma_f32_16x16x32_bf16(a0, w, acc[0][nt], 0, 0, 0);
            acc[1][nt] = __builtin_amdgcn_mfma_f32_16x16x32_bf16(a1, w, acc[1][nt], 0, 0, 0);
        }
    }
    #pragma unroll
    for (int fh = 0; fh < 2; ++fh) {
        #pragma unroll
        for (int nt = 0; nt < 4; ++nt) {
            int col = n0 + nt * 16 + l16;
            if (MODE == 0 && n0 >= 384) {
                // V columns: transposed into vt (bf16), pos-permuted within 64-key chunk.
                // tokens tl..tl+3 -> g0..g0+3 (g0 4-aligned) -> 4 CONSECUTIVE pos.
                int cv = col - 384;               // br*64 + head*32 + d
                int row0 = m0 + fh * 16 + quad * 4;
                int bb_ = row0 >> 12, tl = row0 & 4095;
                int g0 = g_of(cv >> 6, tl);
                int k = g0 & 63, c = k >> 4, m = k & 15;   // m&3 == 0
                int pp = (g0 & ~63) + ((c >> 1) << 5) + ((m >> 2) << 3) + ((c & 1) << 2);
                unsigned short* vrow = vt + ((size_t)((bb_ * 6 + (cv >> 5)) * 32 + (cv & 31)) << 12);
                ushort4 w4;
                w4.x = f2b(acc[fh][nt][0]);
                w4.y = f2b(acc[fh][nt][1]);
                w4.z = f2b(acc[fh][nt][2]);
                w4.w = f2b(acc[fh][nt][3]);
                *reinterpret_cast<ushort4*>(vrow + pp) = w4;
            } else {
                #pragma unroll
                for (int r = 0; r < 4; ++r) {
                    int row = m0 + fh * 16 + quad * 4 + r;
                    float v = acc[fh][nt][r];
                    if (MODE == 0 && col < 192) v *= 0.17677669529663689f;
                    if (MODE >= 1) v += bias[col];
                    if (MODE == 2) v = 0.5f * v * (1.0f + erff(v * 0.70710678118654752f));
                    size_t o = (size_t)row * N + col;
                    if (MODE == 0 || MODE == 2) ((unsigned short*)out)[o] = f2b(v);
                    else                        ((float*)out)[o] = v + resid[o];
                }
            }
        }
    }
}

// ---------------- MFMA windowed attention (no-max softmax, swapped-QK in-register P) ------
// window shapes: br0=(16,16,4), br1=(16,4,16), br2=(4,16,16); S=1024, hd=32
__device__ __forceinline__ int tok_of(int br, int wb, int q) {
    if (br == 0) return ((q >> 6) << 8) | (((q >> 2) & 15) << 4) | (wb << 2) | (q & 3);
    else if (br == 1) return ((q >> 6) << 8) | (((wb << 2) + ((q >> 4) & 3)) << 4) | (q & 15);
    else return (((wb << 2) + (q >> 8)) << 8) | (q & 255);
}

// SPLIT=1: full 16 kt tiles per block, normalize + write attb bf16 (grid 768)
// SPLIT=2: 8 kt tiles per block, write f32 partial O (po) + partial denom (pl) (grid 1536)
// NO LDS, NO BARRIERS: S^T = mfma(K,Q) puts the whole P-row for query l16 in-lane;
// exp+pack produce the PV A-fragments directly in registers (vt's pos permutation
// matches). K/V fragments prefetched one iteration deep.
template <int SPLIT>
__global__ __launch_bounds__(256) void attn_mfma(const unsigned short* __restrict__ qkv,
        const unsigned short* __restrict__ vt,
        unsigned short* __restrict__ attb, float* __restrict__ po, float* __restrict__ pl) {
    const int chunk = 96 * SPLIT;  // (768*SPLIT)/8, grid % 8 == 0 -> bijective
    int hw = blockIdx.x;
    int bid = (hw & 7) * chunk + (hw >> 3);
    int kh, rest;
    if (SPLIT == 2) { kh = bid & 1; rest = bid >> 1; }
    else            { kh = 0;       rest = bid; }
    int qt = rest & 15, head = (rest >> 4) & 1, wb = (rest >> 5) & 3, b = (rest >> 7) & 1, br = rest >> 8;
    int tid = threadIdx.x;
    int wave = tid >> 6, lane = tid & 63, quad = lane >> 4, l16 = lane & 15;
    int coff = br * 64 + head * 32;
    int tb = b << 12;
    // Q b-frag (q pre-scaled in qkv GEMM epilogue): lane holds Q[q=l16][d=quad*8..+8]
    int tq = tok_of(br, wb, qt * 64 + wave * 16 + l16);
    short8 aq = *reinterpret_cast<const short8*>(qkv + (size_t)(tb + tq) * 576 + coff + quad * 8);
    floatx4 o0 = {}, o1 = {};
    float lsum = 0.f;                // partial softmax denom for query l16

    const int NT = 16 / SPLIT;
    const int kc0 = kh * NT * 64;
    const size_t stp = (size_t)((br == 2) ? 64 : 256) * 576;  // K token step per kt

    // K fragment pointers (affine in kt -> pointer-stepped); A-frag: K[key=l16][d=quad*8..]
    const unsigned short* kpA = qkv + (size_t)(tb + tok_of(br, wb, kc0 + l16))      * 576 + 192 + coff + quad * 8;
    const unsigned short* kpB = qkv + (size_t)(tb + tok_of(br, wb, kc0 + 16 + l16)) * 576 + 192 + coff + quad * 8;
    const unsigned short* kpC = qkv + (size_t)(tb + tok_of(br, wb, kc0 + 32 + l16)) * 576 + 192 + coff + quad * 8;
    const unsigned short* kpD = qkv + (size_t)(tb + tok_of(br, wb, kc0 + 48 + l16)) * 576 + 192 + coff + quad * 8;
    // V^T fragment pointers into vt: rows d = l16 / l16+16, cols = pos (step 64/iter)
    const unsigned short* vsl = vt + ((size_t)((b * 6 + br * 2 + head) * 32) << 12) + (wb << 10) + kc0 + quad * 8;
    const unsigned short* v0p = vsl + ((size_t)l16 << 12);
    const unsigned short* v1p = vsl + ((size_t)(l16 + 16) << 12);

    // prefetch iteration 0's fragments
    short8 k0 = *reinterpret_cast<const short8*>(kpA);
    short8 k1 = *reinterpret_cast<const short8*>(kpB);
    short8 k2 = *reinterpret_cast<const short8*>(kpC);
    short8 k3 = *reinterpret_cast<const short8*>(kpD);
    short8 vb00 = *reinterpret_cast<const short8*>(v0p);
    short8 vb01 = *reinterpret_cast<const short8*>(v0p + 32);
    short8 vb10 = *reinterpret_cast<const short8*>(v1p);
    short8 vb11 = *reinterpret_cast<const short8*>(v1p + 32);

    for (int it = 0; it < NT; ++it) {
        short8 ck0 = k0, ck1 = k1, ck2 = k2, ck3 = k3;
        short8 cv00 = vb00, cv01 = vb01, cv10 = vb10, cv11 = vb11;
        // issue next iteration's global loads now; their latency hides under
        // QK + exp/pack + PV of the current iteration
        if (it + 1 < NT) {
            kpA += stp; kpB += stp; kpC += stp; kpD += stp;
            v0p += 64; v1p += 64;
            k0 = *reinterpret_cast<const short8*>(kpA);
            k1 = *reinterpret_cast<const short8*>(kpB);
            k2 = *reinterpret_cast<const short8*>(kpC);
            k3 = *reinterpret_cast<const short8*>(kpD);
            vb00 = *reinterpret_cast<const short8*>(v0p);
            vb01 = *reinterpret_cast<const short8*>(v0p + 32);
            vb10 = *reinterpret_cast<const short8*>(v1p);
            vb11 = *reinterpret_cast<const short8*>(v1p + 32);
        }
        // S^T = K Q^T: lane (quad,l16) gets S[q=l16][key=c*16+quad*4+r] in s_c[r]
        floatx4 z = {};
        floatx4 s0 = __builtin_amdgcn_mfma_f32_16x16x32_bf16(ck0, aq, z, 0, 0, 0);
        floatx4 s1 = __builtin_amdgcn_mfma_f32_16x16x32_bf16(ck1, aq, z, 0, 0, 0);
        floatx4 s2 = __builtin_amdgcn_mfma_f32_16x16x32_bf16(ck2, aq, z, 0, 0, 0);
        floatx4 s3 = __builtin_amdgcn_mfma_f32_16x16x32_bf16(ck3, aq, z, 0, 0, 0);
        // exp (no max subtraction: |s|≲8 with LN'd inputs); pack in-register into
        // the two PV A-fragments: pa0 = P[pos quad*8..+8] of pos 0..31 (c=0,1),
        // pa1 = same for pos 32..63 (c=2,3). vt columns use the matching permutation.
        float p00 = __expf(s0[0]), p01 = __expf(s0[1]), p02 = __expf(s0[2]), p03 = __expf(s0[3]);
        float p10 = __expf(s1[0]), p11 = __expf(s1[1]), p12 = __expf(s1[2]), p13 = __expf(s1[3]);
        float p20 = __expf(s2[0]), p21 = __expf(s2[1]), p22 = __expf(s2[2]), p23 = __expf(s2[3]);
        float p30 = __expf(s3[0]), p31 = __expf(s3[1]), p32 = __expf(s3[2]), p33 = __expf(s3[3]);
        lsum += ((p00 + p01) + (p02 + p03)) + ((p10 + p11) + (p12 + p13))
              + ((p20 + p21) + (p22 + p23)) + ((p30 + p31) + (p32 + p33));
        uint4 ua, ub;
        ua.x = pk2(p00, p01); ua.y = pk2(p02, p03); ua.z = pk2(p10, p11); ua.w = pk2(p12, p13);
        ub.x = pk2(p20, p21); ub.y = pk2(p22, p23); ub.z = pk2(p30, p31); ub.w = pk2(p32, p33);
        short8 pa0 = __builtin_bit_cast(short8, ua);
        short8 pa1 = __builtin_bit_cast(short8, ub);
        // O += P V entirely from registers
        o0 = __builtin_amdgcn_mfma_f32_16x16x32_bf16(pa0, cv00, o0, 0, 0, 0);
        o0 = __builtin_amdgcn_mfma_f32_16x16x32_bf16(pa1, cv01, o0, 0, 0, 0);
        o1 = __builtin_amdgcn_mfma_f32_16x16x32_bf16(pa0, cv10, o1, 0, 0, 0);
        o1 = __builtin_amdgcn_mfma_f32_16x16x32_bf16(pa1, cv11, o1, 0, 0, 0);
    }
    // denom for query l16: sum the 4 quads' partials (lanes l16, l16+16, l16+32, l16+48)
    lsum += __shfl_xor(lsum, 16);
    lsum += __shfl_xor(lsum, 32);
    if (SPLIT == 2) {
        // write f32 partials: O-half and denom-half are purely additive (no-max softmax)
        #pragma unroll
        for (int r = 0; r < 4; ++r) {
            float dv = __shfl(lsum, quad * 4 + r);   // denom(q=quad*4+r), uniform exec
            int q = qt * 64 + wave * 16 + quad * 4 + r;
            int t = tok_of(br, wb, q);
            size_t o = ((size_t)(kh << 13) + tb + t) * 192 + coff;
            po[o + l16]      = o0[r];
            po[o + 16 + l16] = o1[r];
            if (l16 == 0) pl[(size_t)((kh << 13) + tb + t) * 6 + br * 2 + head] = dv;
        }
    } else {
        #pragma unroll
        for (int r = 0; r < 4; ++r) {
            float inv = 1.0f / __shfl(lsum, quad * 4 + r);
            int q = qt * 64 + wave * 16 + quad * 4 + r;
            int t = tok_of(br, wb, q);
            size_t o = (size_t)(tb + t) * 192 + coff;
            attb[o + l16]      = f2b(o0[r] * inv);
            attb[o + 16 + l16] = f2b(o1[r] * inv);
        }
    }
}

// combine split-K halves: attb = (po0 + po1) / (pl0 + pl1), bf16
__global__ __launch_bounds__(256) void attn_combine(const float* __restrict__ po,
        const float* __restrict__ pl, unsigned short* __restrict__ attb) {
    int token = (blockIdx.x << 2) + (threadIdx.x >> 6);
    int lane = threadIdx.x & 63;
    const float* r0 = po + (size_t)token * 192;
    const float* r1 = r0 + (size_t)8192 * 192;
    const float* q0 = pl + (size_t)token * 6;
    const float* q1 = q0 + (size_t)8192 * 6;
    unsigned short* orow = attb + (size_t)token * 192;
    #pragma unroll
    for (int sgm = 0; sgm < 3; ++sgm) {
        int d = lane + sgm * 64;
        int g = d >> 5;                       // br*2 + head
        float denom = q0[g] + q1[g];
        orow[d] = f2b((r0[d] + r1[d]) / denom);
    }
}

// ---------------- LN over rows of (B*L, 192): f32 in -> bf16 out ----------------
__global__ __launch_bounds__(256) void ln_kernel(const float* __restrict__ in,
        const float* __restrict__ g, const float* __restrict__ bb, unsigned short* __restrict__ out) {
    int token = (blockIdx.x << 2) + (threadIdx.x >> 6);
    int lane = threadIdx.x & 63;
    const float* row = in + (size_t)token * 192;
    float v0 = row[lane], v1 = row[lane + 64], v2 = row[lane + 128];
    float s = v0 + v1 + v2, sq = v0 * v0 + v1 * v1 + v2 * v2;
    #pragma unroll
    for (int mask = 1; mask < 64; mask <<= 1) {
        s += __shfl_xor(s, mask);
        sq += __shfl_xor(sq, mask);
    }
    float m = s * (1.f / 192.f);
    float var = sq * (1.f / 192.f) - m * m;
    float rsd = rsqrtf(var + 1e-5f);
    unsigned short* orow = out + (size_t)token * 192;
    orow[lane]       = f2b((v0 - m) * rsd * g[lane]       + bb[lane]);
    orow[lane + 64]  = f2b((v1 - m) * rsd * g[lane + 64]  + bb[lane + 64]);
    orow[lane + 128] = f2b((v2 - m) * rsd * g[lane + 128] + bb[lane + 128]);
}

// ---------------- final transpose (B*L,C) f32 -> (B,C,4096) out dtype per flag ----------------
__global__ __launch_bounds__(256) void unprep_kernel(const float* __restrict__ xs,
                                                     void* __restrict__ out,
                                                     const int* __restrict__ flag) {
    __shared__ float tile[192][33];
    int tid = threadIdx.x;
    int t0 = blockIdx.x * 32;
    int b = t0 >> 12, ts = t0 & 4095;
    for (int idx = tid; idx < 32 * 192; idx += 256) {
        int tt = idx / 192, c = idx % 192;
        tile[c][tt] = xs[(size_t)(t0 + tt) * 192 + c];
    }
    __syncthreads();
    int f = *flag;
    for (int idx = tid; idx < 192 * 32; idx += 256) {
        int c = idx >> 5, tt = idx & 31;
        float v = tile[c][tt];
        int o = ((b * 192 + c) << 12) + ts + tt;
        if (f) ((float*)out)[o] = v;
        else   ((unsigned short*)out)[o] = f2b(v);
    }
}

extern "C" void kernel_launch(void* const* d_in, const int* in_sizes, int n_in,
                              void* d_out, int out_size, void* d_ws, size_t ws_size,
                              hipStream_t stream) {
    float* ws = (float*)d_ws;

    // small fp32 vectors: b_proj, g1, b1, g2, b2, b_fc1, b_fc2 (1920 floats)
    float* vbase = ws;
    float* bprojf = vbase + 0;
    float* g1f    = vbase + 192;
    float* b1f    = vbase + 384;
    float* g2f    = vbase + 576;
    float* b2f    = vbase + 768;
    float* bfc1f  = vbase + 960;
    float* bfc2f  = vbase + 1728;

    // transposed bf16 weights (N x K), 442368 ushorts
    unsigned short* wbase = (unsigned short*)(ws + 1920);
    unsigned short* wqkvT = wbase + 0;
    unsigned short* wprojT = wbase + 110592;
    unsigned short* wfc1T = wbase + 147456;
    unsigned short* wfc2T = wbase + 294912;

    size_t p = 1920 + 442368 / 2;           // float offset after weights
    float* xt = ws + p; p += SZ;            // fp32 residual stream (xs)
    unsigned short* img = (unsigned short*)(ws + p); p += SZ / 2;   // bf16; also lnb
    size_t pQ = p;
    unsigned short* qkv = (unsigned short*)(ws + pQ);               // bf16 8192x576
    unsigned short* hbuf = (unsigned short*)(ws + pQ);              // bf16 8192x768 (aliases qkv)
    p = pQ + 8192 * 768 / 2;
    unsigned short* attb = (unsigned short*)(ws + p); p += SZ / 2;  // bf16
    int* flag = (int*)(ws + p); p += 16;
    // pre-transposed V: vt[b][br*2+head][d=32][pos=4096] bf16 (written by qkv GEMM epilogue)
    unsigned short* vtb = (unsigned short*)(ws + p); p += SZ / 2;
    // split-K attention partials (f32): 2 halves x (8192 x 192) O + (8192 x 6) denom
    float* po = ws + p; p += (size_t)2 * 8192 * 192;
    float* pl = ws + p; p += (size_t)2 * 8192 * 6;
    bool split_ok = ws_size >= p * sizeof(float);
    float* xs = xt;
    unsigned short* lnb = img;

    WPA wa;
    wa.s[0] = d_in[1];  wa.s[1] = d_in[2];  wa.s[2] = d_in[8];  wa.s[3] = d_in[10];
    wa.s[4] = d_in[3];  wa.s[5] = d_in[4];  wa.s[6] = d_in[5];  wa.s[7] = d_in[6];
    wa.s[8] = d_in[7];  wa.s[9] = d_in[9];  wa.s[10] = d_in[11];

    detect_kernel<<<dim3(1), dim3(256), 0, stream>>>((const unsigned short*)d_in[0], flag);
    wprep_kernel<<<dim3(1736), dim3(256), 0, stream>>>(wa, wbase, vbase, flag);
    prep_kernel<<<dim3(256), dim3(256), 0, stream>>>(d_in[0], flag, g1f, b1f, xt, img);
    // qkv: 2-wave blocks (1152 blocks); V columns go transposed+permuted into vtb
    mfma_gemm<0, 2><<<dim3(128, 9), dim3(128), 0, stream>>>(
        img, wqkvT, nullptr, nullptr, qkv, vtb, 576, 192);
    if (split_ok) {
        attn_mfma<2><<<dim3(1536), dim3(256), 0, stream>>>(qkv, vtb, nullptr, po, pl);
        attn_combine<<<dim3(2048), dim3(256), 0, stream>>>(po, pl, attb);
    } else {
        attn_mfma<1><<<dim3(768), dim3(256), 0, stream>>>(qkv, vtb, attb, nullptr, nullptr);
    }
    // proj: 1-wave blocks (768 blocks, 3/CU — every CU busy)
    mfma_gemm<1, 1><<<dim3(256, 3), dim3(64), 0, stream>>>(
        attb, wprojT, bprojf, xt, xs, nullptr, 192, 192);
    ln_kernel<<<dim3(2048), dim3(256), 0, stream>>>(xs, g2f, b2f, lnb);
    // fc1: 2-wave blocks (1536 blocks, 6/CU)
    mfma_gemm<2, 2><<<dim3(128, 12), dim3(128), 0, stream>>>(
        lnb, wfc1T, bfc1f, nullptr, hbuf, nullptr, 768, 192);
    // fc2: 1-wave blocks (768 blocks, 3/CU)
    mfma_gemm<3, 1><<<dim3(256, 3), dim3(64), 0, stream>>>(
        hbuf, wfc2T, bfc2f, xs, xs, nullptr, 192, 768);
    unprep_kernel<<<dim3(256), dim3(256), 0, stream>>>(xs, d_out, flag);
}

// Round 9
// 204.972 us; speedup vs baseline: 1.1016x; 1.0786x over previous
//
#include <hip/hip_runtime.h>
#include <hip/hip_bf16.h>

typedef __hip_bfloat16 bf16;
typedef short short8 __attribute__((ext_vector_type(8)));
typedef float floatx4 __attribute__((ext_vector_type(4)));

#define SZ (8192*192)   // one (B*L, C) fp32 plane in floats

__device__ __forceinline__ unsigned short f2b(float f) {
    unsigned u = __builtin_bit_cast(unsigned, f);
    u += 0x7FFFu + ((u >> 16) & 1u);   // RNE
    return (unsigned short)(u >> 16);
}
__device__ __forceinline__ float b2f(unsigned short h) {
    unsigned u = ((unsigned)h) << 16;
    return __builtin_bit_cast(float, u);
}
__device__ __forceinline__ unsigned pk2(float a, float b) {
    // packed bf16 pair (a in low half / lower address)
    return ((unsigned)f2b(b) << 16) | (unsigned)f2b(a);
}

// ---------------- dtype detect: bf16 vs fp32 inputs ----------------
__global__ void detect_kernel(const unsigned short* __restrict__ x16, int* __restrict__ flag) {
    __shared__ int cnt;
    if (threadIdx.x == 0) cnt = 0;
    __syncthreads();
    int c = 0;
    for (int i = threadIdx.x; i < 8192; i += 256) {
        int e = (x16[i] >> 7) & 0xFF;
        if (e >= 152) c++;
    }
    if (c) atomicAdd(&cnt, c);
    __syncthreads();
    if (threadIdx.x == 0) *flag = (cnt >= 32) ? 1 : 0;
}

// ---------------- fused weight transpose (->bf16 NxK) + small-vector cvt (->f32) ----------------
struct WPA { const void* s[11]; };
// s[]: w_qkv, w_proj, w_fc1, w_fc2, b_proj, g1, b1, g2, b2, b_fc1, b_fc2

__global__ __launch_bounds__(256) void wprep_kernel(WPA a, unsigned short* __restrict__ wdst,
                                                    float* __restrict__ vdst,
                                                    const int* __restrict__ flag) {
    int i = blockIdx.x * 256 + threadIdx.x;
    int f = *flag;
    if (i < 442368) {
        int seg, base, K, N;
        if (i < 110592)      { seg = 0; base = 0;      K = 192; N = 576; }
        else if (i < 147456) { seg = 1; base = 110592; K = 192; N = 192; }
        else if (i < 294912) { seg = 2; base = 147456; K = 192; N = 768; }
        else                 { seg = 3; base = 294912; K = 768; N = 192; }
        int j = i - base;
        int n = j / K, k = j - n * K;
        size_t src = (size_t)k * N + n;
        float v = f ? ((const float*)a.s[seg])[src] : b2f(((const unsigned short*)a.s[seg])[src]);
        wdst[i] = f2b(v);
    } else if (i < 444288) {
        int j = i - 442368;
        int seg, off;
        if (j < 960)       { seg = 4 + j / 192; off = j % 192; }
        else if (j < 1728) { seg = 9; off = j - 960; }
        else               { seg = 10; off = j - 1728; }
        float v = f ? ((const float*)a.s[seg])[off] : b2f(((const unsigned short*)a.s[seg])[off]);
        vdst[j] = v;
    }
}

// ---------------- prep: x (B,C,4096) -> xt=2x (B*L,C) f32 and img=LN bf16 ----------------
__global__ __launch_bounds__(256) void prep_kernel(const void* __restrict__ xin,
        const int* __restrict__ flag,
        const float* __restrict__ g1, const float* __restrict__ b1,
        float* __restrict__ xt, unsigned short* __restrict__ img) {
    __shared__ float tile[192][33];
    __shared__ float mu[32], rs[32];
    int tid = threadIdx.x;
    int t0 = blockIdx.x * 32;
    int b = t0 >> 12;
    int ts = t0 & 4095;
    int f = *flag;
    for (int idx = tid; idx < 192 * 32; idx += 256) {
        int c = idx >> 5, tt = idx & 31;
        int gi = ((b * 192 + c) << 12) + ts + tt;
        float raw = f ? ((const float*)xin)[gi] : b2f(((const unsigned short*)xin)[gi]);
        tile[c][tt] = 2.0f * raw;
    }
    __syncthreads();
    {
        // 8 threads per token, 24 channels each, then 3-step shfl reduce within the 8-lane group
        int tt = tid >> 3, j = tid & 7;
        int c0 = j * 24;
        float s = 0.f, sq = 0.f;
        #pragma unroll
        for (int i = 0; i < 24; ++i) { float v = tile[c0 + i][tt]; s += v; sq += v * v; }
        s += __shfl_xor(s, 1); sq += __shfl_xor(sq, 1);
        s += __shfl_xor(s, 2); sq += __shfl_xor(sq, 2);
        s += __shfl_xor(s, 4); sq += __shfl_xor(sq, 4);
        if (j == 0) {
            float m = s * (1.0f / 192.0f);
            float var = sq * (1.0f / 192.0f) - m * m;
            mu[tt] = m;
            rs[tt] = rsqrtf(var + 1e-5f);
        }
    }
    __syncthreads();
    for (int idx = tid; idx < 32 * 192; idx += 256) {
        int tt = idx / 192, c = idx % 192;
        float v = tile[c][tt];
        int o = (t0 + tt) * 192 + c;
        xt[o] = v;
        img[o] = f2b((v - mu[tt]) * rs[tt] * g1[c] + b1[c]);
    }
}

// window-position index of token t (within batch) for branch br: g = wb*1024 + q.
// Inverse of tok_of. 4 consecutive tokens (t 4-aligned) -> 4 consecutive g.
__device__ __forceinline__ int g_of(int br, int t) {
    if (br == 0) return (((t >> 2) & 3) << 10) | ((t >> 8) << 6) | (((t >> 4) & 15) << 2) | (t & 3);
    if (br == 1) return (((t >> 6) & 3) << 10) | ((t >> 8) << 6) | (((t >> 4) & 3) << 4) | (t & 15);
    return t;
}

// ---------------- MFMA GEMM, per-wave 32x64 tile (FH=2), W waves/block ----------------
// MODE 0 (qkv): Q cols (<192) -> qkv bf16, pre-scaled by 1/sqrt(32).
//   K cols (192..384) -> kt packed MFMA A-frag tiles: per (b,brh,wb,chunk,c) a 16x32
//     tile [key m][d], so the attention wave load l16*32+quad*8 is 1KB contiguous.
//   V cols (>=384) -> vt packed B-frag tiles: per (b,brh,wb,chunk,tidx) a 16x32 tile
//     [d&15][pos&31]; pos(key) = (c>>1)*32 + (m>>2)*8 + (c&1)*4 + (m&3) matches the
//     in-register P layout of the swapped-QK attention (verified R8).
// MODE 1: out f32  = acc + bias + resid                            (proj)
// MODE 2: out bf16 = gelu(acc + bias)                              (fc1)
// MODE 3: out f32  = acc + bias + resid (in-place resid==out ok)   (fc2)
template <int MODE, int W>
__global__ __launch_bounds__(64 * W) void mfma_gemm(const unsigned short* __restrict__ A,
        const unsigned short* __restrict__ WT, const float* __restrict__ bias,
        const float* __restrict__ resid, void* __restrict__ out,
        unsigned short* __restrict__ kt, unsigned short* __restrict__ vt, int N, int K) {
    int wave = threadIdx.x >> 6, lane = threadIdx.x & 63;
    int quad = lane >> 4, l16 = lane & 15;
    int m0 = blockIdx.x * (32 * W) + wave * 32, n0 = blockIdx.y * 64;
    const unsigned short* ap = A + (size_t)(m0 + l16) * K + quad * 8;
    const unsigned short* wp = WT + (size_t)(n0 + l16) * K + quad * 8;
    floatx4 acc[2][4] = {};
    #pragma unroll 2
    for (int kc = 0; kc < K; kc += 32) {
        short8 a0 = *reinterpret_cast<const short8*>(ap + kc);
        short8 a1 = *reinterpret_cast<const short8*>(ap + (size_t)16 * K + kc);
        #pragma unroll
        for (int nt = 0; nt < 4; ++nt) {
            short8 w = *reinterpret_cast<const short8*>(wp + (size_t)nt * 16 * K + kc);
            acc[0][nt] = __builtin_amdgcn_mfma_f32_16x16x32_bf16(a0, w, acc[0][nt], 0, 0, 0);
            acc[1][nt] = __builtin_amdgcn_mfma_f32_16x16x32_bf16(a1, w, acc[1][nt], 0, 0, 0);
        }
    }
    #pragma unroll
    for (int fh = 0; fh < 2; ++fh) {
        #pragma unroll
        for (int nt = 0; nt < 4; ++nt) {
            int col = n0 + nt * 16 + l16;
            if (MODE == 0 && n0 >= 384) {
                // V -> packed vt tiles
                int cv = col - 384;               // brh*32 + d
                int d = cv & 31, brh = cv >> 5;
                int row0 = m0 + fh * 16 + quad * 4;
                int bb_ = row0 >> 12, tl = row0 & 4095;
                int g0 = g_of(brh >> 1, tl);
                int wb2 = g0 >> 10, k = g0 & 63, c = k >> 4, m = k & 15;   // m&3==0
                int pos = ((c >> 1) << 5) + ((m >> 2) << 3) + ((c & 1) << 2);
                int chunk = (g0 & 1023) >> 6;
                int tidx = ((d >> 4) << 1) | (pos >> 5);
                unsigned short* tile = vt + (((((size_t)(bb_ * 6 + brh) * 4 + wb2) * 16 + chunk) * 4 + tidx) << 9);
                ushort4 w4;
                w4.x = f2b(acc[fh][nt][0]);
                w4.y = f2b(acc[fh][nt][1]);
                w4.z = f2b(acc[fh][nt][2]);
                w4.w = f2b(acc[fh][nt][3]);
                *reinterpret_cast<ushort4*>(tile + (d & 15) * 32 + (pos & 31)) = w4;
            } else if (MODE == 0 && n0 >= 192) {
                // K -> packed kt tiles (4 stride-64B 2B stores; epilogue-only cost)
                int ck = col - 192;
                int d = ck & 31, brh = ck >> 5;
                int row0 = m0 + fh * 16 + quad * 4;
                int bb_ = row0 >> 12, tl = row0 & 4095;
                int g0 = g_of(brh >> 1, tl);
                int wb2 = g0 >> 10, k = g0 & 63, c = k >> 4, m = k & 15;   // m&3==0
                int chunk = (g0 & 1023) >> 6;
                unsigned short* tile = kt + (((((size_t)(bb_ * 6 + brh) * 4 + wb2) * 16 + chunk) * 4 + c) << 9);
                tile[m * 32 + d]       = f2b(acc[fh][nt][0]);
                tile[(m + 1) * 32 + d] = f2b(acc[fh][nt][1]);
                tile[(m + 2) * 32 + d] = f2b(acc[fh][nt][2]);
                tile[(m + 3) * 32 + d] = f2b(acc[fh][nt][3]);
            } else {
                #pragma unroll
                for (int r = 0; r < 4; ++r) {
                    int row = m0 + fh * 16 + quad * 4 + r;
                    float v = acc[fh][nt][r];
                    if (MODE == 0 && col < 192) v *= 0.17677669529663689f;
                    if (MODE >= 1) v += bias[col];
                    if (MODE == 2) v = 0.5f * v * (1.0f + erff(v * 0.70710678118654752f));
                    size_t o = (size_t)row * N + col;
                    if (MODE == 0 || MODE == 2) ((unsigned short*)out)[o] = f2b(v);
                    else                        ((float*)out)[o] = v + resid[o];
                }
            }
        }
    }
}

// ---------------- MFMA windowed attention (no-max softmax, swapped-QK in-register P) ------
// window shapes: br0=(16,16,4), br1=(16,4,16), br2=(4,16,16); S=1024, hd=32
__device__ __forceinline__ int tok_of(int br, int wb, int q) {
    if (br == 0) return ((q >> 6) << 8) | (((q >> 2) & 15) << 4) | (wb << 2) | (q & 3);
    else if (br == 1) return ((q >> 6) << 8) | (((wb << 2) + ((q >> 4) & 3)) << 4) | (q & 15);
    else return (((wb << 2) + (q >> 8)) << 8) | (q & 255);
}

// SPLIT=1: full 16 kt tiles per block, normalize + write attb bf16 (grid 768)
// SPLIT=2: 8 kt tiles per block, write f32 partial O (po) + partial denom (pl) (grid 1536)
// NO LDS, NO BARRIERS, FULLY-COALESCED: all 8 hot-loop loads are contiguous 1KB wave
// transactions from the packed kt/vt tile buffers. S^T = mfma(K,Q) keeps P lane-local;
// exp+pack produce PV A-fragments in registers. One-deep register prefetch.
template <int SPLIT>
__global__ __launch_bounds__(256) void attn_mfma(const unsigned short* __restrict__ qkv,
        const unsigned short* __restrict__ kt, const unsigned short* __restrict__ vt,
        unsigned short* __restrict__ attb, float* __restrict__ po, float* __restrict__ pl) {
    const int chunk = 96 * SPLIT;  // (768*SPLIT)/8, grid % 8 == 0 -> bijective
    int hw = blockIdx.x;
    int bid = (hw & 7) * chunk + (hw >> 3);
    int kh, rest;
    if (SPLIT == 2) { kh = bid & 1; rest = bid >> 1; }
    else            { kh = 0;       rest = bid; }
    int qt = rest & 15, head = (rest >> 4) & 1, wb = (rest >> 5) & 3, b = (rest >> 7) & 1, br = rest >> 8;
    int tid = threadIdx.x;
    int wave = tid >> 6, lane = tid & 63, quad = lane >> 4, l16 = lane & 15;
    int coff = br * 64 + head * 32;
    int tb = b << 12;
    // Q b-frag (q pre-scaled in qkv GEMM epilogue): lane holds Q[q=l16][d=quad*8..+8]
    int tq = tok_of(br, wb, qt * 64 + wave * 16 + l16);
    short8 aq = *reinterpret_cast<const short8*>(qkv + (size_t)(tb + tq) * 576 + coff + quad * 8);
    floatx4 o0 = {}, o1 = {};
    float lsum = 0.f;                // partial softmax denom for query l16

    const int NT = 16 / SPLIT;
    // packed tile base for this (b, brh, wb), offset to the kh half, plus lane offset
    const size_t base_idx = ((((size_t)(b * 6 + br * 2 + head) * 4 + wb) * 16 + kh * NT) << 11)
                          + l16 * 32 + quad * 8;
    const unsigned short* kp = kt + base_idx;
    const unsigned short* vp = vt + base_idx;

    // prefetch iteration 0's fragments (all 1KB-coalesced wave loads)
    short8 k0 = *reinterpret_cast<const short8*>(kp);
    short8 k1 = *reinterpret_cast<const short8*>(kp + 512);
    short8 k2 = *reinterpret_cast<const short8*>(kp + 1024);
    short8 k3 = *reinterpret_cast<const short8*>(kp + 1536);
    short8 vb00 = *reinterpret_cast<const short8*>(vp);
    short8 vb01 = *reinterpret_cast<const short8*>(vp + 512);
    short8 vb10 = *reinterpret_cast<const short8*>(vp + 1024);
    short8 vb11 = *reinterpret_cast<const short8*>(vp + 1536);

    for (int it = 0; it < NT; ++it) {
        short8 ck0 = k0, ck1 = k1, ck2 = k2, ck3 = k3;
        short8 cv00 = vb00, cv01 = vb01, cv10 = vb10, cv11 = vb11;
        // issue next iteration's global loads now; their latency hides under
        // QK + exp/pack + PV of the current iteration
        if (it + 1 < NT) {
            kp += 2048; vp += 2048;
            k0 = *reinterpret_cast<const short8*>(kp);
            k1 = *reinterpret_cast<const short8*>(kp + 512);
            k2 = *reinterpret_cast<const short8*>(kp + 1024);
            k3 = *reinterpret_cast<const short8*>(kp + 1536);
            vb00 = *reinterpret_cast<const short8*>(vp);
            vb01 = *reinterpret_cast<const short8*>(vp + 512);
            vb10 = *reinterpret_cast<const short8*>(vp + 1024);
            vb11 = *reinterpret_cast<const short8*>(vp + 1536);
        }
        // S^T = K Q^T: lane (quad,l16) gets S[q=l16][key=c*16+quad*4+r] in s_c[r]
        floatx4 z = {};
        floatx4 s0 = __builtin_amdgcn_mfma_f32_16x16x32_bf16(ck0, aq, z, 0, 0, 0);
        floatx4 s1 = __builtin_amdgcn_mfma_f32_16x16x32_bf16(ck1, aq, z, 0, 0, 0);
        floatx4 s2 = __builtin_amdgcn_mfma_f32_16x16x32_bf16(ck2, aq, z, 0, 0, 0);
        floatx4 s3 = __builtin_amdgcn_mfma_f32_16x16x32_bf16(ck3, aq, z, 0, 0, 0);
        // exp (no max subtraction: |s|≲8 with LN'd inputs); pack in-register into
        // the two PV A-fragments (pos permutation matches vt tiles)
        float p00 = __expf(s0[0]), p01 = __expf(s0[1]), p02 = __expf(s0[2]), p03 = __expf(s0[3]);
        float p10 = __expf(s1[0]), p11 = __expf(s1[1]), p12 = __expf(s1[2]), p13 = __expf(s1[3]);
        float p20 = __expf(s2[0]), p21 = __expf(s2[1]), p22 = __expf(s2[2]), p23 = __expf(s2[3]);
        float p30 = __expf(s3[0]), p31 = __expf(s3[1]), p32 = __expf(s3[2]), p33 = __expf(s3[3]);
        lsum += ((p00 + p01) + (p02 + p03)) + ((p10 + p11) + (p12 + p13))
              + ((p20 + p21) + (p22 + p23)) + ((p30 + p31) + (p32 + p33));
        uint4 ua, ub;
        ua.x = pk2(p00, p01); ua.y = pk2(p02, p03); ua.z = pk2(p10, p11); ua.w = pk2(p12, p13);
        ub.x = pk2(p20, p21); ub.y = pk2(p22, p23); ub.z = pk2(p30, p31); ub.w = pk2(p32, p33);
        short8 pa0 = __builtin_bit_cast(short8, ua);
        short8 pa1 = __builtin_bit_cast(short8, ub);
        // O += P V entirely from registers
        o0 = __builtin_amdgcn_mfma_f32_16x16x32_bf16(pa0, cv00, o0, 0, 0, 0);
        o0 = __builtin_amdgcn_mfma_f32_16x16x32_bf16(pa1, cv01, o0, 0, 0, 0);
        o1 = __builtin_amdgcn_mfma_f32_16x16x32_bf16(pa0, cv10, o1, 0, 0, 0);
        o1 = __builtin_amdgcn_mfma_f32_16x16x32_bf16(pa1, cv11, o1, 0, 0, 0);
    }
    // denom for query l16: sum the 4 quads' partials (lanes l16, l16+16, l16+32, l16+48)
    lsum += __shfl_xor(lsum, 16);
    lsum += __shfl_xor(lsum, 32);
    if (SPLIT == 2) {
        // write f32 partials: O-half and denom-half are purely additive (no-max softmax)
        #pragma unroll
        for (int r = 0; r < 4; ++r) {
            float dv = __shfl(lsum, quad * 4 + r);   // denom(q=quad*4+r), uniform exec
            int q = qt * 64 + wave * 16 + quad * 4 + r;
            int t = tok_of(br, wb, q);
            size_t o = ((size_t)(kh << 13) + tb + t) * 192 + coff;
            po[o + l16]      = o0[r];
            po[o + 16 + l16] = o1[r];
            if (l16 == 0) pl[(size_t)((kh << 13) + tb + t) * 6 + br * 2 + head] = dv;
        }
    } else {
        #pragma unroll
        for (int r = 0; r < 4; ++r) {
            float inv = 1.0f / __shfl(lsum, quad * 4 + r);
            int q = qt * 64 + wave * 16 + quad * 4 + r;
            int t = tok_of(br, wb, q);
            size_t o = (size_t)(tb + t) * 192 + coff;
            attb[o + l16]      = f2b(o0[r] * inv);
            attb[o + 16 + l16] = f2b(o1[r] * inv);
        }
    }
}

// combine split-K halves: attb = (po0 + po1) / (pl0 + pl1), bf16
__global__ __launch_bounds__(256) void attn_combine(const float* __restrict__ po,
        const float* __restrict__ pl, unsigned short* __restrict__ attb) {
    int token = (blockIdx.x << 2) + (threadIdx.x >> 6);
    int lane = threadIdx.x & 63;
    const float* r0 = po + (size_t)token * 192;
    const float* r1 = r0 + (size_t)8192 * 192;
    const float* q0 = pl + (size_t)token * 6;
    const float* q1 = q0 + (size_t)8192 * 6;
    unsigned short* orow = attb + (size_t)token * 192;
    #pragma unroll
    for (int sgm = 0; sgm < 3; ++sgm) {
        int d = lane + sgm * 64;
        int g = d >> 5;                       // br*2 + head
        float denom = q0[g] + q1[g];
        orow[d] = f2b((r0[d] + r1[d]) / denom);
    }
}

// ---------------- LN over rows of (B*L, 192): f32 in -> bf16 out ----------------
__global__ __launch_bounds__(256) void ln_kernel(const float* __restrict__ in,
        const float* __restrict__ g, const float* __restrict__ bb, unsigned short* __restrict__ out) {
    int token = (blockIdx.x << 2) + (threadIdx.x >> 6);
    int lane = threadIdx.x & 63;
    const float* row = in + (size_t)token * 192;
    float v0 = row[lane], v1 = row[lane + 64], v2 = row[lane + 128];
    float s = v0 + v1 + v2, sq = v0 * v0 + v1 * v1 + v2 * v2;
    #pragma unroll
    for (int mask = 1; mask < 64; mask <<= 1) {
        s += __shfl_xor(s, mask);
        sq += __shfl_xor(sq, mask);
    }
    float m = s * (1.f / 192.f);
    float var = sq * (1.f / 192.f) - m * m;
    float rsd = rsqrtf(var + 1e-5f);
    unsigned short* orow = out + (size_t)token * 192;
    orow[lane]       = f2b((v0 - m) * rsd * g[lane]       + bb[lane]);
    orow[lane + 64]  = f2b((v1 - m) * rsd * g[lane + 64]  + bb[lane + 64]);
    orow[lane + 128] = f2b((v2 - m) * rsd * g[lane + 128] + bb[lane + 128]);
}

// ---------------- final transpose (B*L,C) f32 -> (B,C,4096) out dtype per flag ----------------
__global__ __launch_bounds__(256) void unprep_kernel(const float* __restrict__ xs,
                                                     void* __restrict__ out,
                                                     const int* __restrict__ flag) {
    __shared__ float tile[192][33];
    int tid = threadIdx.x;
    int t0 = blockIdx.x * 32;
    int b = t0 >> 12, ts = t0 & 4095;
    for (int idx = tid; idx < 32 * 192; idx += 256) {
        int tt = idx / 192, c = idx % 192;
        tile[c][tt] = xs[(size_t)(t0 + tt) * 192 + c];
    }
    __syncthreads();
    int f = *flag;
    for (int idx = tid; idx < 192 * 32; idx += 256) {
        int c = idx >> 5, tt = idx & 31;
        float v = tile[c][tt];
        int o = ((b * 192 + c) << 12) + ts + tt;
        if (f) ((float*)out)[o] = v;
        else   ((unsigned short*)out)[o] = f2b(v);
    }
}

extern "C" void kernel_launch(void* const* d_in, const int* in_sizes, int n_in,
                              void* d_out, int out_size, void* d_ws, size_t ws_size,
                              hipStream_t stream) {
    float* ws = (float*)d_ws;

    // small fp32 vectors: b_proj, g1, b1, g2, b2, b_fc1, b_fc2 (1920 floats)
    float* vbase = ws;
    float* bprojf = vbase + 0;
    float* g1f    = vbase + 192;
    float* b1f    = vbase + 384;
    float* g2f    = vbase + 576;
    float* b2f    = vbase + 768;
    float* bfc1f  = vbase + 960;
    float* bfc2f  = vbase + 1728;

    // transposed bf16 weights (N x K), 442368 ushorts
    unsigned short* wbase = (unsigned short*)(ws + 1920);
    unsigned short* wqkvT = wbase + 0;
    unsigned short* wprojT = wbase + 110592;
    unsigned short* wfc1T = wbase + 147456;
    unsigned short* wfc2T = wbase + 294912;

    size_t p = 1920 + 442368 / 2;           // float offset after weights
    float* xt = ws + p; p += SZ;            // fp32 residual stream (xs)
    unsigned short* img = (unsigned short*)(ws + p); p += SZ / 2;   // bf16; also lnb
    size_t pQ = p;
    unsigned short* qkv = (unsigned short*)(ws + pQ);               // bf16 8192x576
    unsigned short* hbuf = (unsigned short*)(ws + pQ);              // bf16 8192x768 (aliases qkv)
    p = pQ + 8192 * 768 / 2;
    unsigned short* attb = (unsigned short*)(ws + p); p += SZ / 2;  // bf16
    int* flag = (int*)(ws + p); p += 16;
    // packed K tiles: [b][brh=6][wb=4][chunk=16][ctile=4][16x32] bf16 (3MB)
    unsigned short* ktb = (unsigned short*)(ws + p); p += SZ / 2;
    // packed V tiles: [b][brh=6][wb=4][chunk=16][tidx=4][16x32] bf16 (3MB)
    unsigned short* vtb = (unsigned short*)(ws + p); p += SZ / 2;
    // split-K attention partials (f32): 2 halves x (8192 x 192) O + (8192 x 6) denom
    float* po = ws + p; p += (size_t)2 * 8192 * 192;
    float* pl = ws + p; p += (size_t)2 * 8192 * 6;
    bool split_ok = ws_size >= p * sizeof(float);
    float* xs = xt;
    unsigned short* lnb = img;

    WPA wa;
    wa.s[0] = d_in[1];  wa.s[1] = d_in[2];  wa.s[2] = d_in[8];  wa.s[3] = d_in[10];
    wa.s[4] = d_in[3];  wa.s[5] = d_in[4];  wa.s[6] = d_in[5];  wa.s[7] = d_in[6];
    wa.s[8] = d_in[7];  wa.s[9] = d_in[9];  wa.s[10] = d_in[11];

    detect_kernel<<<dim3(1), dim3(256), 0, stream>>>((const unsigned short*)d_in[0], flag);
    wprep_kernel<<<dim3(1736), dim3(256), 0, stream>>>(wa, wbase, vbase, flag);
    prep_kernel<<<dim3(256), dim3(256), 0, stream>>>(d_in[0], flag, g1f, b1f, xt, img);
    // qkv: 2-wave blocks (1152 blocks); K/V columns go into packed kt/vt tiles
    mfma_gemm<0, 2><<<dim3(128, 9), dim3(128), 0, stream>>>(
        img, wqkvT, nullptr, nullptr, qkv, ktb, vtb, 576, 192);
    if (split_ok) {
        attn_mfma<2><<<dim3(1536), dim3(256), 0, stream>>>(qkv, ktb, vtb, nullptr, po, pl);
        attn_combine<<<dim3(2048), dim3(256), 0, stream>>>(po, pl, attb);
    } else {
        attn_mfma<1><<<dim3(768), dim3(256), 0, stream>>>(qkv, ktb, vtb, attb, nullptr, nullptr);
    }
    // proj: 1-wave blocks (768 blocks, 3/CU — every CU busy)
    mfma_gemm<1, 1><<<dim3(256, 3), dim3(64), 0, stream>>>(
        attb, wprojT, bprojf, xt, xs, nullptr, nullptr, 192, 192);
    ln_kernel<<<dim3(2048), dim3(256), 0, stream>>>(xs, g2f, b2f, lnb);
    // fc1: 2-wave blocks (1536 blocks, 6/CU)
    mfma_gemm<2, 2><<<dim3(128, 12), dim3(128), 0, stream>>>(
        lnb, wfc1T, bfc1f, nullptr, hbuf, nullptr, nullptr, 768, 192);
    // fc2: 1-wave blocks (768 blocks, 3/CU)
    mfma_gemm<3, 1><<<dim3(256, 3), dim3(64), 0, stream>>>(
        hbuf, wfc2T, bfc2f, xs, xs, nullptr, nullptr, 192, 768);
    unprep_kernel<<<dim3(256), dim3(256), 0, stream>>>(xs, d_out, flag);
}

// Round 10
// 183.948 us; speedup vs baseline: 1.2275x; 1.1143x over previous
//
#include <hip/hip_runtime.h>
#include <hip/hip_bf16.h>

typedef __hip_bfloat16 bf16;
typedef short short8 __attribute__((ext_vector_type(8)));
typedef float floatx4 __attribute__((ext_vector_type(4)));

#define SZ (8192*192)   // one (B*L, C) fp32 plane in floats

__device__ __forceinline__ unsigned short f2b(float f) {
    unsigned u = __builtin_bit_cast(unsigned, f);
    u += 0x7FFFu + ((u >> 16) & 1u);   // RNE
    return (unsigned short)(u >> 16);
}
__device__ __forceinline__ float b2f(unsigned short h) {
    unsigned u = ((unsigned)h) << 16;
    return __builtin_bit_cast(float, u);
}
__device__ __forceinline__ unsigned pk2(float a, float b) {
    // packed bf16 pair (a in low half / lower address)
    return ((unsigned)f2b(b) << 16) | (unsigned)f2b(a);
}

// ---------------- dtype detect: bf16 vs fp32 inputs ----------------
__global__ void detect_kernel(const unsigned short* __restrict__ x16, int* __restrict__ flag) {
    __shared__ int cnt;
    if (threadIdx.x == 0) cnt = 0;
    __syncthreads();
    int c = 0;
    for (int i = threadIdx.x; i < 8192; i += 256) {
        int e = (x16[i] >> 7) & 0xFF;
        if (e >= 152) c++;
    }
    if (c) atomicAdd(&cnt, c);
    __syncthreads();
    if (threadIdx.x == 0) *flag = (cnt >= 32) ? 1 : 0;
}

// ---------------- fused weight transpose -> bf16 MFMA-fragment-packed tiles ------------
// Packed layout per weight (N x K): chunk ci = (n>>6)*(K>>5) + (k>>5), 2048-elem tiles;
// addr = ci*2048 + ((n>>4)&3)*512 + (n&15)*32 + (k&31). GEMM wave loads are then
// contiguous 1KB transactions.
struct WPA { const void* s[11]; };
// s[]: w_qkv, w_proj, w_fc1, w_fc2, b_proj, g1, b1, g2, b2, b_fc1, b_fc2

__global__ __launch_bounds__(256) void wprep_kernel(WPA a, unsigned short* __restrict__ wdst,
                                                    float* __restrict__ vdst,
                                                    const int* __restrict__ flag) {
    int i = blockIdx.x * 256 + threadIdx.x;
    int f = *flag;
    if (i < 442368) {
        int seg, base, K, N;
        if (i < 110592)      { seg = 0; base = 0;      K = 192; N = 576; }
        else if (i < 147456) { seg = 1; base = 110592; K = 192; N = 192; }
        else if (i < 294912) { seg = 2; base = 147456; K = 192; N = 768; }
        else                 { seg = 3; base = 294912; K = 768; N = 192; }
        int j = i - base;
        int n = j / K, k = j - n * K;
        size_t src = (size_t)k * N + n;
        float v = f ? ((const float*)a.s[seg])[src] : b2f(((const unsigned short*)a.s[seg])[src]);
        int ci = (n >> 6) * (K >> 5) + (k >> 5);
        int off = (ci << 11) + (((n >> 4) & 3) << 9) + ((n & 15) << 5) + (k & 31);
        wdst[base + off] = f2b(v);
    } else if (i < 444288) {
        int j = i - 442368;
        int seg, off;
        if (j < 960)       { seg = 4 + j / 192; off = j % 192; }
        else if (j < 1728) { seg = 9; off = j - 960; }
        else               { seg = 10; off = j - 1728; }
        float v = f ? ((const float*)a.s[seg])[off] : b2f(((const unsigned short*)a.s[seg])[off]);
        vdst[j] = v;
    }
}

// ---------------- prep: x (B,C,4096) -> xt=2x (B*L,C) f32 and img=LN bf16 ----------------
__global__ __launch_bounds__(256) void prep_kernel(const void* __restrict__ xin,
        const int* __restrict__ flag,
        const float* __restrict__ g1, const float* __restrict__ b1,
        float* __restrict__ xt, unsigned short* __restrict__ img) {
    __shared__ float tile[192][33];
    __shared__ float mu[32], rs[32];
    int tid = threadIdx.x;
    int t0 = blockIdx.x * 32;
    int b = t0 >> 12;
    int ts = t0 & 4095;
    int f = *flag;
    for (int idx = tid; idx < 192 * 32; idx += 256) {
        int c = idx >> 5, tt = idx & 31;
        int gi = ((b * 192 + c) << 12) + ts + tt;
        float raw = f ? ((const float*)xin)[gi] : b2f(((const unsigned short*)xin)[gi]);
        tile[c][tt] = 2.0f * raw;
    }
    __syncthreads();
    {
        int tt = tid >> 3, j = tid & 7;
        int c0 = j * 24;
        float s = 0.f, sq = 0.f;
        #pragma unroll
        for (int i = 0; i < 24; ++i) { float v = tile[c0 + i][tt]; s += v; sq += v * v; }
        s += __shfl_xor(s, 1); sq += __shfl_xor(sq, 1);
        s += __shfl_xor(s, 2); sq += __shfl_xor(sq, 2);
        s += __shfl_xor(s, 4); sq += __shfl_xor(sq, 4);
        if (j == 0) {
            float m = s * (1.0f / 192.0f);
            float var = sq * (1.0f / 192.0f) - m * m;
            mu[tt] = m;
            rs[tt] = rsqrtf(var + 1e-5f);
        }
    }
    __syncthreads();
    for (int idx = tid; idx < 32 * 192; idx += 256) {
        int tt = idx / 192, c = idx % 192;
        float v = tile[c][tt];
        int o = (t0 + tt) * 192 + c;
        xt[o] = v;
        img[o] = f2b((v - mu[tt]) * rs[tt] * g1[c] + b1[c]);
    }
}

// window-position index of token t (within batch) for branch br: g = wb*1024 + q.
// Inverse of tok_of. 4 consecutive tokens (t 4-aligned) -> 4 consecutive g.
__device__ __forceinline__ int g_of(int br, int t) {
    if (br == 0) return (((t >> 2) & 3) << 10) | ((t >> 8) << 6) | (((t >> 4) & 15) << 2) | (t & 3);
    if (br == 1) return (((t >> 6) & 3) << 10) | ((t >> 8) << 6) | (((t >> 4) & 3) << 4) | (t & 15);
    return t;
}

// ---------------- MFMA GEMM, per-wave 32x64 tile (FH=2), W waves/block ----------------
// Weights come from the fragment-packed layout (see wprep) -> 1KB coalesced loads.
// MODE 0 (qkv): Q cols (<192, pre-scaled 1/sqrt(32)) -> qt packed tiles
//     [b][brh][wb][qchunk=64][16x32]; K cols (192..384) -> kt packed tiles
//     [b][brh][wb][chunk=16][c=4][16x32]; V cols (>=384) -> vt packed tiles
//     [b][brh][wb][chunk=16][tidx=4][16x32] with pos permutation matching the
//     in-register P layout (verified R8/R9). qkv buffer is NOT written.
// MODE 1: out f32  = acc + bias + resid                            (proj)
// MODE 2: out bf16 = gelu(acc + bias)                              (fc1)
// MODE 3: out f32  = acc + bias + resid (in-place resid==out ok)   (fc2)
template <int MODE, int W>
__global__ __launch_bounds__(64 * W) void mfma_gemm(const unsigned short* __restrict__ A,
        const unsigned short* __restrict__ WT, const float* __restrict__ bias,
        const float* __restrict__ resid, void* __restrict__ out,
        unsigned short* __restrict__ qt, unsigned short* __restrict__ kt,
        unsigned short* __restrict__ vt, int N, int K) {
    int wave = threadIdx.x >> 6, lane = threadIdx.x & 63;
    int quad = lane >> 4, l16 = lane & 15;
    int m0 = blockIdx.x * (32 * W) + wave * 32, n0 = blockIdx.y * 64;
    const unsigned short* ap = A + (size_t)(m0 + l16) * K + quad * 8;
    const unsigned short* wpB = WT + (((size_t)blockIdx.y * (K >> 5)) << 11) + l16 * 32 + quad * 8;
    floatx4 acc[2][4] = {};
    #pragma unroll 2
    for (int kc = 0; kc < K; kc += 32) {
        short8 a0 = *reinterpret_cast<const short8*>(ap + kc);
        short8 a1 = *reinterpret_cast<const short8*>(ap + (size_t)16 * K + kc);
        const unsigned short* wc = wpB + (((size_t)(kc >> 5)) << 11);
        #pragma unroll
        for (int nt = 0; nt < 4; ++nt) {
            short8 w = *reinterpret_cast<const short8*>(wc + nt * 512);
            acc[0][nt] = __builtin_amdgcn_mfma_f32_16x16x32_bf16(a0, w, acc[0][nt], 0, 0, 0);
            acc[1][nt] = __builtin_amdgcn_mfma_f32_16x16x32_bf16(a1, w, acc[1][nt], 0, 0, 0);
        }
    }
    #pragma unroll
    for (int fh = 0; fh < 2; ++fh) {
        #pragma unroll
        for (int nt = 0; nt < 4; ++nt) {
            int col = n0 + nt * 16 + l16;
            if (MODE == 0 && n0 >= 384) {
                // V -> packed vt tiles
                int cv = col - 384;               // brh*32 + d
                int d = cv & 31, brh = cv >> 5;
                int row0 = m0 + fh * 16 + quad * 4;
                int bb_ = row0 >> 12, tl = row0 & 4095;
                int g0 = g_of(brh >> 1, tl);
                int wb2 = g0 >> 10, k = g0 & 63, c = k >> 4, m = k & 15;   // m&3==0
                int pos = ((c >> 1) << 5) + ((m >> 2) << 3) + ((c & 1) << 2);
                int chunk = (g0 & 1023) >> 6;
                int tidx = ((d >> 4) << 1) | (pos >> 5);
                unsigned short* tile = vt + (((((size_t)(bb_ * 6 + brh) * 4 + wb2) * 16 + chunk) * 4 + tidx) << 9);
                ushort4 w4;
                w4.x = f2b(acc[fh][nt][0]);
                w4.y = f2b(acc[fh][nt][1]);
                w4.z = f2b(acc[fh][nt][2]);
                w4.w = f2b(acc[fh][nt][3]);
                *reinterpret_cast<ushort4*>(tile + (d & 15) * 32 + (pos & 31)) = w4;
            } else if (MODE == 0 && n0 >= 192) {
                // K -> packed kt tiles (4 stride-64B 2B stores; epilogue-only cost)
                int ck = col - 192;
                int d = ck & 31, brh = ck >> 5;
                int row0 = m0 + fh * 16 + quad * 4;
                int bb_ = row0 >> 12, tl = row0 & 4095;
                int g0 = g_of(brh >> 1, tl);
                int wb2 = g0 >> 10, k = g0 & 63, c = k >> 4, m = k & 15;   // m&3==0
                int chunk = (g0 & 1023) >> 6;
                unsigned short* tile = kt + (((((size_t)(bb_ * 6 + brh) * 4 + wb2) * 16 + chunk) * 4 + c) << 9);
                tile[m * 32 + d]       = f2b(acc[fh][nt][0]);
                tile[(m + 1) * 32 + d] = f2b(acc[fh][nt][1]);
                tile[(m + 2) * 32 + d] = f2b(acc[fh][nt][2]);
                tile[(m + 3) * 32 + d] = f2b(acc[fh][nt][3]);
            } else if (MODE == 0) {
                // Q -> packed qt tiles (pre-scaled)
                int d = col & 31, brh = col >> 5;
                int row0 = m0 + fh * 16 + quad * 4;
                int bb_ = row0 >> 12, tl = row0 & 4095;
                int g0 = g_of(brh >> 1, tl);
                int wb2 = g0 >> 10, q = g0 & 1023;
                int chunk = q >> 4, m = q & 15;   // m&3==0
                unsigned short* tile = qt + ((((size_t)(bb_ * 6 + brh) * 4 + wb2) * 64 + chunk) << 9);
                tile[m * 32 + d]       = f2b(acc[fh][nt][0] * 0.17677669529663689f);
                tile[(m + 1) * 32 + d] = f2b(acc[fh][nt][1] * 0.17677669529663689f);
                tile[(m + 2) * 32 + d] = f2b(acc[fh][nt][2] * 0.17677669529663689f);
                tile[(m + 3) * 32 + d] = f2b(acc[fh][nt][3] * 0.17677669529663689f);
            } else {
                #pragma unroll
                for (int r = 0; r < 4; ++r) {
                    int row = m0 + fh * 16 + quad * 4 + r;
                    float v = acc[fh][nt][r];
                    if (MODE >= 1) v += bias[col];
                    if (MODE == 2) v = 0.5f * v * (1.0f + erff(v * 0.70710678118654752f));
                    size_t o = (size_t)row * N + col;
                    if (MODE == 2) ((unsigned short*)out)[o] = f2b(v);
                    else           ((float*)out)[o] = v + resid[o];
                }
            }
        }
    }
}

// ---------------- MFMA windowed attention (no-max softmax, swapped-QK in-register P) ------
// window shapes: br0=(16,16,4), br1=(16,4,16), br2=(4,16,16); S=1024, hd=32
__device__ __forceinline__ int tok_of(int br, int wb, int q) {
    if (br == 0) return ((q >> 6) << 8) | (((q >> 2) & 15) << 4) | (wb << 2) | (q & 3);
    else if (br == 1) return ((q >> 6) << 8) | (((wb << 2) + ((q >> 4) & 3)) << 4) | (q & 15);
    else return (((wb << 2) + (q >> 8)) << 8) | (q & 255);
}

// Single-pass (16 kt tiles), NO LDS, NO BARRIERS, FULLY-COALESCED: all hot-loop loads
// (Q, K, V) are contiguous 1KB wave transactions from packed tile buffers.
// S^T = mfma(K,Q) keeps P lane-local; exp+pack produce PV A-fragments in registers.
// One-deep register prefetch. Grid 768 (%8==0 -> bijective XCD swizzle).
__global__ __launch_bounds__(256) void attn_mfma(const unsigned short* __restrict__ qt,
        const unsigned short* __restrict__ kt, const unsigned short* __restrict__ vt,
        unsigned short* __restrict__ attb) {
    int hw = blockIdx.x;
    int bid = (hw & 7) * 96 + (hw >> 3);
    int qti = bid & 15, head = (bid >> 4) & 1, wb = (bid >> 5) & 3, b = (bid >> 7) & 1, br = bid >> 8;
    int tid = threadIdx.x;
    int wave = tid >> 6, lane = tid & 63, quad = lane >> 4, l16 = lane & 15;
    int coff = br * 64 + head * 32;
    int brh = br * 2 + head;
    int tb = b << 12;
    // Q b-frag from packed qt (1KB coalesced): lane holds Q[q=l16][d=quad*8..+8]
    size_t qbase = ((((size_t)(b * 6 + brh) * 4 + wb) * 64 + qti * 4 + wave) << 9) + l16 * 32 + quad * 8;
    short8 aq = *reinterpret_cast<const short8*>(qt + qbase);
    floatx4 o0 = {}, o1 = {};
    float lsum = 0.f;                // partial softmax denom for query l16

    const size_t kvbase = ((((size_t)(b * 6 + brh) * 4 + wb) * 16) << 11) + l16 * 32 + quad * 8;
    const unsigned short* kp = kt + kvbase;
    const unsigned short* vp = vt + kvbase;

    // prefetch iteration 0's fragments (all 1KB-coalesced wave loads)
    short8 k0 = *reinterpret_cast<const short8*>(kp);
    short8 k1 = *reinterpret_cast<const short8*>(kp + 512);
    short8 k2 = *reinterpret_cast<const short8*>(kp + 1024);
    short8 k3 = *reinterpret_cast<const short8*>(kp + 1536);
    short8 vb00 = *reinterpret_cast<const short8*>(vp);
    short8 vb01 = *reinterpret_cast<const short8*>(vp + 512);
    short8 vb10 = *reinterpret_cast<const short8*>(vp + 1024);
    short8 vb11 = *reinterpret_cast<const short8*>(vp + 1536);

    for (int it = 0; it < 16; ++it) {
        short8 ck0 = k0, ck1 = k1, ck2 = k2, ck3 = k3;
        short8 cv00 = vb00, cv01 = vb01, cv10 = vb10, cv11 = vb11;
        // issue next iteration's global loads now; their latency hides under
        // QK + exp/pack + PV of the current iteration
        if (it + 1 < 16) {
            kp += 2048; vp += 2048;
            k0 = *reinterpret_cast<const short8*>(kp);
            k1 = *reinterpret_cast<const short8*>(kp + 512);
            k2 = *reinterpret_cast<const short8*>(kp + 1024);
            k3 = *reinterpret_cast<const short8*>(kp + 1536);
            vb00 = *reinterpret_cast<const short8*>(vp);
            vb01 = *reinterpret_cast<const short8*>(vp + 512);
            vb10 = *reinterpret_cast<const short8*>(vp + 1024);
            vb11 = *reinterpret_cast<const short8*>(vp + 1536);
        }
        // S^T = K Q^T: lane (quad,l16) gets S[q=l16][key=c*16+quad*4+r] in s_c[r]
        floatx4 z = {};
        floatx4 s0 = __builtin_amdgcn_mfma_f32_16x16x32_bf16(ck0, aq, z, 0, 0, 0);
        floatx4 s1 = __builtin_amdgcn_mfma_f32_16x16x32_bf16(ck1, aq, z, 0, 0, 0);
        floatx4 s2 = __builtin_amdgcn_mfma_f32_16x16x32_bf16(ck2, aq, z, 0, 0, 0);
        floatx4 s3 = __builtin_amdgcn_mfma_f32_16x16x32_bf16(ck3, aq, z, 0, 0, 0);
        // exp (no max subtraction: |s|≲8 with LN'd inputs); pack in-register into
        // the two PV A-fragments (pos permutation matches vt tiles)
        float p00 = __expf(s0[0]), p01 = __expf(s0[1]), p02 = __expf(s0[2]), p03 = __expf(s0[3]);
        float p10 = __expf(s1[0]), p11 = __expf(s1[1]), p12 = __expf(s1[2]), p13 = __expf(s1[3]);
        float p20 = __expf(s2[0]), p21 = __expf(s2[1]), p22 = __expf(s2[2]), p23 = __expf(s2[3]);
        float p30 = __expf(s3[0]), p31 = __expf(s3[1]), p32 = __expf(s3[2]), p33 = __expf(s3[3]);
        lsum += ((p00 + p01) + (p02 + p03)) + ((p10 + p11) + (p12 + p13))
              + ((p20 + p21) + (p22 + p23)) + ((p30 + p31) + (p32 + p33));
        uint4 ua, ub;
        ua.x = pk2(p00, p01); ua.y = pk2(p02, p03); ua.z = pk2(p10, p11); ua.w = pk2(p12, p13);
        ub.x = pk2(p20, p21); ub.y = pk2(p22, p23); ub.z = pk2(p30, p31); ub.w = pk2(p32, p33);
        short8 pa0 = __builtin_bit_cast(short8, ua);
        short8 pa1 = __builtin_bit_cast(short8, ub);
        // O += P V entirely from registers
        o0 = __builtin_amdgcn_mfma_f32_16x16x32_bf16(pa0, cv00, o0, 0, 0, 0);
        o0 = __builtin_amdgcn_mfma_f32_16x16x32_bf16(pa1, cv01, o0, 0, 0, 0);
        o1 = __builtin_amdgcn_mfma_f32_16x16x32_bf16(pa0, cv10, o1, 0, 0, 0);
        o1 = __builtin_amdgcn_mfma_f32_16x16x32_bf16(pa1, cv11, o1, 0, 0, 0);
    }
    // denom for query l16: sum the 4 quads' partials (lanes l16, l16+16, l16+32, l16+48)
    lsum += __shfl_xor(lsum, 16);
    lsum += __shfl_xor(lsum, 32);
    #pragma unroll
    for (int r = 0; r < 4; ++r) {
        float inv = 1.0f / __shfl(lsum, quad * 4 + r);
        int q = qti * 64 + wave * 16 + quad * 4 + r;
        int t = tok_of(br, wb, q);
        size_t o = (size_t)(tb + t) * 192 + coff;
        attb[o + l16]      = f2b(o0[r] * inv);
        attb[o + 16 + l16] = f2b(o1[r] * inv);
    }
}

// ---------------- LN over rows of (B*L, 192): f32 in -> bf16 out ----------------
__global__ __launch_bounds__(256) void ln_kernel(const float* __restrict__ in,
        const float* __restrict__ g, const float* __restrict__ bb, unsigned short* __restrict__ out) {
    int token = (blockIdx.x << 2) + (threadIdx.x >> 6);
    int lane = threadIdx.x & 63;
    const float* row = in + (size_t)token * 192;
    float v0 = row[lane], v1 = row[lane + 64], v2 = row[lane + 128];
    float s = v0 + v1 + v2, sq = v0 * v0 + v1 * v1 + v2 * v2;
    #pragma unroll
    for (int mask = 1; mask < 64; mask <<= 1) {
        s += __shfl_xor(s, mask);
        sq += __shfl_xor(sq, mask);
    }
    float m = s * (1.f / 192.f);
    float var = sq * (1.f / 192.f) - m * m;
    float rsd = rsqrtf(var + 1e-5f);
    unsigned short* orow = out + (size_t)token * 192;
    orow[lane]       = f2b((v0 - m) * rsd * g[lane]       + bb[lane]);
    orow[lane + 64]  = f2b((v1 - m) * rsd * g[lane + 64]  + bb[lane + 64]);
    orow[lane + 128] = f2b((v2 - m) * rsd * g[lane + 128] + bb[lane + 128]);
}

// ---------------- final transpose (B*L,C) f32 -> (B,C,4096) out dtype per flag ----------------
__global__ __launch_bounds__(256) void unprep_kernel(const float* __restrict__ xs,
                                                     void* __restrict__ out,
                                                     const int* __restrict__ flag) {
    __shared__ float tile[192][33];
    int tid = threadIdx.x;
    int t0 = blockIdx.x * 32;
    int b = t0 >> 12, ts = t0 & 4095;
    for (int idx = tid; idx < 32 * 192; idx += 256) {
        int tt = idx / 192, c = idx % 192;
        tile[c][tt] = xs[(size_t)(t0 + tt) * 192 + c];
    }
    __syncthreads();
    int f = *flag;
    for (int idx = tid; idx < 192 * 32; idx += 256) {
        int c = idx >> 5, tt = idx & 31;
        float v = tile[c][tt];
        int o = ((b * 192 + c) << 12) + ts + tt;
        if (f) ((float*)out)[o] = v;
        else   ((unsigned short*)out)[o] = f2b(v);
    }
}

extern "C" void kernel_launch(void* const* d_in, const int* in_sizes, int n_in,
                              void* d_out, int out_size, void* d_ws, size_t ws_size,
                              hipStream_t stream) {
    float* ws = (float*)d_ws;

    // small fp32 vectors: b_proj, g1, b1, g2, b2, b_fc1, b_fc2 (1920 floats)
    float* vbase = ws;
    float* bprojf = vbase + 0;
    float* g1f    = vbase + 192;
    float* b1f    = vbase + 384;
    float* g2f    = vbase + 576;
    float* b2f    = vbase + 768;
    float* bfc1f  = vbase + 960;
    float* bfc2f  = vbase + 1728;

    // fragment-packed bf16 weights, 442368 ushorts
    unsigned short* wbase = (unsigned short*)(ws + 1920);
    unsigned short* wqkvT = wbase + 0;
    unsigned short* wprojT = wbase + 110592;
    unsigned short* wfc1T = wbase + 147456;
    unsigned short* wfc2T = wbase + 294912;

    size_t p = 1920 + 442368 / 2;           // float offset after weights
    float* xt = ws + p; p += SZ;            // fp32 residual stream (xs)
    unsigned short* img = (unsigned short*)(ws + p); p += SZ / 2;   // bf16; also lnb
    size_t pQ = p;
    unsigned short* hbuf = (unsigned short*)(ws + pQ);              // bf16 8192x768
    p = pQ + 8192 * 768 / 2;
    unsigned short* attb = (unsigned short*)(ws + p); p += SZ / 2;  // bf16
    int* flag = (int*)(ws + p); p += 16;
    // packed Q tiles: [b][brh=6][wb=4][qchunk=64][16x32] bf16 (3MB)
    unsigned short* qtb = (unsigned short*)(ws + p); p += SZ / 2;
    // packed K tiles: [b][brh=6][wb=4][chunk=16][ctile=4][16x32] bf16 (3MB)
    unsigned short* ktb = (unsigned short*)(ws + p); p += SZ / 2;
    // packed V tiles: [b][brh=6][wb=4][chunk=16][tidx=4][16x32] bf16 (3MB)
    unsigned short* vtb = (unsigned short*)(ws + p); p += SZ / 2;
    float* xs = xt;
    unsigned short* lnb = img;

    WPA wa;
    wa.s[0] = d_in[1];  wa.s[1] = d_in[2];  wa.s[2] = d_in[8];  wa.s[3] = d_in[10];
    wa.s[4] = d_in[3];  wa.s[5] = d_in[4];  wa.s[6] = d_in[5];  wa.s[7] = d_in[6];
    wa.s[8] = d_in[7];  wa.s[9] = d_in[9];  wa.s[10] = d_in[11];

    detect_kernel<<<dim3(1), dim3(256), 0, stream>>>((const unsigned short*)d_in[0], flag);
    wprep_kernel<<<dim3(1736), dim3(256), 0, stream>>>(wa, wbase, vbase, flag);
    prep_kernel<<<dim3(256), dim3(256), 0, stream>>>(d_in[0], flag, g1f, b1f, xt, img);
    // qkv: 2-wave blocks (1152 blocks); Q/K/V all go into packed tile buffers
    mfma_gemm<0, 2><<<dim3(128, 9), dim3(128), 0, stream>>>(
        img, wqkvT, nullptr, nullptr, nullptr, qtb, ktb, vtb, 576, 192);
    // attention: single-pass, 768 blocks, fully coalesced packed loads
    attn_mfma<<<dim3(768), dim3(256), 0, stream>>>(qtb, ktb, vtb, attb);
    // proj: 1-wave blocks (768 blocks, 3/CU — every CU busy)
    mfma_gemm<1, 1><<<dim3(256, 3), dim3(64), 0, stream>>>(
        attb, wprojT, bprojf, xt, xs, nullptr, nullptr, nullptr, 192, 192);
    ln_kernel<<<dim3(2048), dim3(256), 0, stream>>>(xs, g2f, b2f, lnb);
    // fc1: 2-wave blocks (1536 blocks, 6/CU)
    mfma_gemm<2, 2><<<dim3(128, 12), dim3(128), 0, stream>>>(
        lnb, wfc1T, bfc1f, nullptr, hbuf, nullptr, nullptr, nullptr, 768, 192);
    // fc2: 1-wave blocks (768 blocks, 3/CU)
    mfma_gemm<3, 1><<<dim3(256, 3), dim3(64), 0, stream>>>(
        hbuf, wfc2T, bfc2f, xs, xs, nullptr, nullptr, nullptr, 192, 768);
    unprep_kernel<<<dim3(256), dim3(256), 0, stream>>>(xs, d_out, flag);
}

// Round 11
// 183.063 us; speedup vs baseline: 1.2335x; 1.0048x over previous
//
#include <hip/hip_runtime.h>
#include <hip/hip_bf16.h>

typedef __hip_bfloat16 bf16;
typedef short short8 __attribute__((ext_vector_type(8)));
typedef float floatx4 __attribute__((ext_vector_type(4)));

#define SZ (8192*192)   // one (B*L, C) fp32 plane in floats

__device__ __forceinline__ unsigned short f2b(float f) {
    unsigned u = __builtin_bit_cast(unsigned, f);
    u += 0x7FFFu + ((u >> 16) & 1u);   // RNE
    return (unsigned short)(u >> 16);
}
__device__ __forceinline__ float b2f(unsigned short h) {
    unsigned u = ((unsigned)h) << 16;
    return __builtin_bit_cast(float, u);
}
__device__ __forceinline__ unsigned pk2(float a, float b) {
    // packed bf16 pair (a in low half / lower address)
    return ((unsigned)f2b(b) << 16) | (unsigned)f2b(a);
}

// ---------------- dtype detect: bf16 vs fp32 inputs ----------------
__global__ void detect_kernel(const unsigned short* __restrict__ x16, int* __restrict__ flag) {
    __shared__ int cnt;
    if (threadIdx.x == 0) cnt = 0;
    __syncthreads();
    int c = 0;
    for (int i = threadIdx.x; i < 8192; i += 256) {
        int e = (x16[i] >> 7) & 0xFF;
        if (e >= 152) c++;
    }
    if (c) atomicAdd(&cnt, c);
    __syncthreads();
    if (threadIdx.x == 0) *flag = (cnt >= 32) ? 1 : 0;
}

// ---------------- fused weight transpose -> bf16 MFMA-fragment-packed tiles ------------
// Packed layout per weight (N x K): chunk ci = (n>>6)*(K>>5) + (k>>5), 2048-elem tiles;
// addr = ci*2048 + ((n>>4)&3)*512 + (n&15)*32 + (k&31). GEMM wave loads are then
// contiguous 1KB transactions.
struct WPA { const void* s[11]; };
// s[]: w_qkv, w_proj, w_fc1, w_fc2, b_proj, g1, b1, g2, b2, b_fc1, b_fc2

__global__ __launch_bounds__(256) void wprep_kernel(WPA a, unsigned short* __restrict__ wdst,
                                                    float* __restrict__ vdst,
                                                    const int* __restrict__ flag) {
    int i = blockIdx.x * 256 + threadIdx.x;
    int f = *flag;
    if (i < 442368) {
        int seg, base, K, N;
        if (i < 110592)      { seg = 0; base = 0;      K = 192; N = 576; }
        else if (i < 147456) { seg = 1; base = 110592; K = 192; N = 192; }
        else if (i < 294912) { seg = 2; base = 147456; K = 192; N = 768; }
        else                 { seg = 3; base = 294912; K = 768; N = 192; }
        int j = i - base;
        int n = j / K, k = j - n * K;
        size_t src = (size_t)k * N + n;
        float v = f ? ((const float*)a.s[seg])[src] : b2f(((const unsigned short*)a.s[seg])[src]);
        int ci = (n >> 6) * (K >> 5) + (k >> 5);
        int off = (ci << 11) + (((n >> 4) & 3) << 9) + ((n & 15) << 5) + (k & 31);
        wdst[base + off] = f2b(v);
    } else if (i < 444288) {
        int j = i - 442368;
        int seg, off;
        if (j < 960)       { seg = 4 + j / 192; off = j % 192; }
        else if (j < 1728) { seg = 9; off = j - 960; }
        else               { seg = 10; off = j - 1728; }
        float v = f ? ((const float*)a.s[seg])[off] : b2f(((const unsigned short*)a.s[seg])[off]);
        vdst[j] = v;
    }
}

// A-operand fragment-packed layout for (M x K) bf16:
// addr = ((row>>4)*(K>>5) + (k>>5))*512 + (row&15)*32 + (k&31)
// -> GEMM A-frag wave load (rows r0..r0+15, cols kc+quad*8) is 1KB contiguous.

// ---------------- prep: x (B,C,4096) -> xt=2x (B*L,C) f32 and img=LN bf16 (packed) --------
__global__ __launch_bounds__(256) void prep_kernel(const void* __restrict__ xin,
        const int* __restrict__ flag,
        const float* __restrict__ g1, const float* __restrict__ b1,
        float* __restrict__ xt, unsigned short* __restrict__ img) {
    __shared__ float tile[192][33];
    __shared__ float mu[32], rs[32];
    int tid = threadIdx.x;
    int t0 = blockIdx.x * 32;
    int b = t0 >> 12;
    int ts = t0 & 4095;
    int f = *flag;
    for (int idx = tid; idx < 192 * 32; idx += 256) {
        int c = idx >> 5, tt = idx & 31;
        int gi = ((b * 192 + c) << 12) + ts + tt;
        float raw = f ? ((const float*)xin)[gi] : b2f(((const unsigned short*)xin)[gi]);
        tile[c][tt] = 2.0f * raw;
    }
    __syncthreads();
    {
        int tt = tid >> 3, j = tid & 7;
        int c0 = j * 24;
        float s = 0.f, sq = 0.f;
        #pragma unroll
        for (int i = 0; i < 24; ++i) { float v = tile[c0 + i][tt]; s += v; sq += v * v; }
        s += __shfl_xor(s, 1); sq += __shfl_xor(sq, 1);
        s += __shfl_xor(s, 2); sq += __shfl_xor(sq, 2);
        s += __shfl_xor(s, 4); sq += __shfl_xor(sq, 4);
        if (j == 0) {
            float m = s * (1.0f / 192.0f);
            float var = sq * (1.0f / 192.0f) - m * m;
            mu[tt] = m;
            rs[tt] = rsqrtf(var + 1e-5f);
        }
    }
    __syncthreads();
    for (int idx = tid; idx < 32 * 192; idx += 256) {
        int tt = idx / 192, c = idx % 192;
        float v = tile[c][tt];
        xt[(t0 + tt) * 192 + c] = v;
        int po = ((((t0 + tt) >> 4) * 6 + (c >> 5)) << 9) + ((tt & 15) << 5) + (c & 31);
        img[po] = f2b((v - mu[tt]) * rs[tt] * g1[c] + b1[c]);
    }
}

// window-position index of token t (within batch) for branch br: g = wb*1024 + q.
// Inverse of tok_of. 4 consecutive tokens (t 4-aligned) -> 4 consecutive g.
__device__ __forceinline__ int g_of(int br, int t) {
    if (br == 0) return (((t >> 2) & 3) << 10) | ((t >> 8) << 6) | (((t >> 4) & 15) << 2) | (t & 3);
    if (br == 1) return (((t >> 6) & 3) << 10) | ((t >> 8) << 6) | (((t >> 4) & 3) << 4) | (t & 15);
    return t;
}

// ---------------- MFMA GEMM, per-wave 32x64 tile (FH=2), W waves/block ----------------
// A and W both come from fragment-packed layouts -> every hot-loop load is a
// contiguous 1KB wave transaction.
// MODE 0 (qkv): Q cols (<192, pre-scaled 1/sqrt(32)) -> qt packed tiles; K cols
//     (192..384) -> kt packed tiles; V cols (>=384) -> vt packed tiles with pos
//     permutation matching the in-register P layout (verified R8/R9/R10).
// MODE 1: out f32  = acc + bias + resid (planar)                   (proj)
// MODE 2: out bf16 = gelu(acc + bias) -> FRAGMENT-PACKED hbuf      (fc1)
// MODE 3: out f32  = acc + bias + resid (planar, in-place ok)      (fc2)
template <int MODE, int W>
__global__ __launch_bounds__(64 * W) void mfma_gemm(const unsigned short* __restrict__ A,
        const unsigned short* __restrict__ WT, const float* __restrict__ bias,
        const float* __restrict__ resid, void* __restrict__ out,
        unsigned short* __restrict__ qt, unsigned short* __restrict__ kt,
        unsigned short* __restrict__ vt, int N, int K) {
    int wave = threadIdx.x >> 6, lane = threadIdx.x & 63;
    int quad = lane >> 4, l16 = lane & 15;
    int m0 = blockIdx.x * (32 * W) + wave * 32, n0 = blockIdx.y * 64;
    const int KT = K >> 5;
    const unsigned short* ap = A + (((size_t)(m0 >> 4) * KT) << 9) + l16 * 32 + quad * 8;
    const size_t a1off = ((size_t)KT) << 9;
    const unsigned short* wpB = WT + (((size_t)blockIdx.y * KT) << 11) + l16 * 32 + quad * 8;
    floatx4 acc[2][4] = {};
    #pragma unroll 2
    for (int kc = 0; kc < K; kc += 32) {
        const unsigned short* ac = ap + (((size_t)(kc >> 5)) << 9);
        short8 a0 = *reinterpret_cast<const short8*>(ac);
        short8 a1 = *reinterpret_cast<const short8*>(ac + a1off);
        const unsigned short* wc = wpB + (((size_t)(kc >> 5)) << 11);
        #pragma unroll
        for (int nt = 0; nt < 4; ++nt) {
            short8 w = *reinterpret_cast<const short8*>(wc + nt * 512);
            acc[0][nt] = __builtin_amdgcn_mfma_f32_16x16x32_bf16(a0, w, acc[0][nt], 0, 0, 0);
            acc[1][nt] = __builtin_amdgcn_mfma_f32_16x16x32_bf16(a1, w, acc[1][nt], 0, 0, 0);
        }
    }
    #pragma unroll
    for (int fh = 0; fh < 2; ++fh) {
        #pragma unroll
        for (int nt = 0; nt < 4; ++nt) {
            int col = n0 + nt * 16 + l16;
            if (MODE == 0 && n0 >= 384) {
                // V -> packed vt tiles
                int cv = col - 384;               // brh*32 + d
                int d = cv & 31, brh = cv >> 5;
                int row0 = m0 + fh * 16 + quad * 4;
                int bb_ = row0 >> 12, tl = row0 & 4095;
                int g0 = g_of(brh >> 1, tl);
                int wb2 = g0 >> 10, k = g0 & 63, c = k >> 4, m = k & 15;   // m&3==0
                int pos = ((c >> 1) << 5) + ((m >> 2) << 3) + ((c & 1) << 2);
                int chunk = (g0 & 1023) >> 6;
                int tidx = ((d >> 4) << 1) | (pos >> 5);
                unsigned short* tile = vt + (((((size_t)(bb_ * 6 + brh) * 4 + wb2) * 16 + chunk) * 4 + tidx) << 9);
                ushort4 w4;
                w4.x = f2b(acc[fh][nt][0]);
                w4.y = f2b(acc[fh][nt][1]);
                w4.z = f2b(acc[fh][nt][2]);
                w4.w = f2b(acc[fh][nt][3]);
                *reinterpret_cast<ushort4*>(tile + (d & 15) * 32 + (pos & 31)) = w4;
            } else if (MODE == 0 && n0 >= 192) {
                // K -> packed kt tiles (4 stride-64B 2B stores; epilogue-only cost)
                int ck = col - 192;
                int d = ck & 31, brh = ck >> 5;
                int row0 = m0 + fh * 16 + quad * 4;
                int bb_ = row0 >> 12, tl = row0 & 4095;
                int g0 = g_of(brh >> 1, tl);
                int wb2 = g0 >> 10, k = g0 & 63, c = k >> 4, m = k & 15;   // m&3==0
                int chunk = (g0 & 1023) >> 6;
                unsigned short* tile = kt + (((((size_t)(bb_ * 6 + brh) * 4 + wb2) * 16 + chunk) * 4 + c) << 9);
                tile[m * 32 + d]       = f2b(acc[fh][nt][0]);
                tile[(m + 1) * 32 + d] = f2b(acc[fh][nt][1]);
                tile[(m + 2) * 32 + d] = f2b(acc[fh][nt][2]);
                tile[(m + 3) * 32 + d] = f2b(acc[fh][nt][3]);
            } else if (MODE == 0) {
                // Q -> packed qt tiles (pre-scaled)
                int d = col & 31, brh = col >> 5;
                int row0 = m0 + fh * 16 + quad * 4;
                int bb_ = row0 >> 12, tl = row0 & 4095;
                int g0 = g_of(brh >> 1, tl);
                int wb2 = g0 >> 10, q = g0 & 1023;
                int chunk = q >> 4, m = q & 15;   // m&3==0
                unsigned short* tile = qt + ((((size_t)(bb_ * 6 + brh) * 4 + wb2) * 64 + chunk) << 9);
                tile[m * 32 + d]       = f2b(acc[fh][nt][0] * 0.17677669529663689f);
                tile[(m + 1) * 32 + d] = f2b(acc[fh][nt][1] * 0.17677669529663689f);
                tile[(m + 2) * 32 + d] = f2b(acc[fh][nt][2] * 0.17677669529663689f);
                tile[(m + 3) * 32 + d] = f2b(acc[fh][nt][3] * 0.17677669529663689f);
            } else {
                #pragma unroll
                for (int r = 0; r < 4; ++r) {
                    int row = m0 + fh * 16 + quad * 4 + r;
                    float v = acc[fh][nt][r] + bias[col];
                    if (MODE == 2) {
                        v = 0.5f * v * (1.0f + erff(v * 0.70710678118654752f));
                        size_t o = (((size_t)(row >> 4) * (N >> 5) + (col >> 5)) << 9)
                                 + ((row & 15) << 5) + (col & 31);
                        ((unsigned short*)out)[o] = f2b(v);
                    } else {
                        size_t o = (size_t)row * N + col;
                        ((float*)out)[o] = v + resid[o];
                    }
                }
            }
        }
    }
}

// ---------------- MFMA windowed attention (no-max softmax, swapped-QK in-register P) ------
// window shapes: br0=(16,16,4), br1=(16,4,16), br2=(4,16,16); S=1024, hd=32
__device__ __forceinline__ int tok_of(int br, int wb, int q) {
    if (br == 0) return ((q >> 6) << 8) | (((q >> 2) & 15) << 4) | (wb << 2) | (q & 3);
    else if (br == 1) return ((q >> 6) << 8) | (((wb << 2) + ((q >> 4) & 3)) << 4) | (q & 15);
    else return (((wb << 2) + (q >> 8)) << 8) | (q & 255);
}

// Single-pass (16 kt tiles), NO LDS, NO BARRIERS, FULLY-COALESCED: all hot-loop loads
// (Q, K, V) are contiguous 1KB wave transactions from packed tile buffers.
// S^T = mfma(K,Q) keeps P lane-local; exp+pack produce PV A-fragments in registers.
// Output attb is written FRAGMENT-PACKED (K=192) for the proj GEMM.
__global__ __launch_bounds__(256) void attn_mfma(const unsigned short* __restrict__ qt,
        const unsigned short* __restrict__ kt, const unsigned short* __restrict__ vt,
        unsigned short* __restrict__ attb) {
    int hw = blockIdx.x;
    int bid = (hw & 7) * 96 + (hw >> 3);
    int qti = bid & 15, head = (bid >> 4) & 1, wb = (bid >> 5) & 3, b = (bid >> 7) & 1, br = bid >> 8;
    int tid = threadIdx.x;
    int wave = tid >> 6, lane = tid & 63, quad = lane >> 4, l16 = lane & 15;
    int coff = br * 64 + head * 32;
    int brh = br * 2 + head;
    int tb = b << 12;
    // Q b-frag from packed qt (1KB coalesced): lane holds Q[q=l16][d=quad*8..+8]
    size_t qbase = ((((size_t)(b * 6 + brh) * 4 + wb) * 64 + qti * 4 + wave) << 9) + l16 * 32 + quad * 8;
    short8 aq = *reinterpret_cast<const short8*>(qt + qbase);
    floatx4 o0 = {}, o1 = {};
    float lsum = 0.f;                // partial softmax denom for query l16

    const size_t kvbase = ((((size_t)(b * 6 + brh) * 4 + wb) * 16) << 11) + l16 * 32 + quad * 8;
    const unsigned short* kp = kt + kvbase;
    const unsigned short* vp = vt + kvbase;

    // prefetch iteration 0's fragments (all 1KB-coalesced wave loads)
    short8 k0 = *reinterpret_cast<const short8*>(kp);
    short8 k1 = *reinterpret_cast<const short8*>(kp + 512);
    short8 k2 = *reinterpret_cast<const short8*>(kp + 1024);
    short8 k3 = *reinterpret_cast<const short8*>(kp + 1536);
    short8 vb00 = *reinterpret_cast<const short8*>(vp);
    short8 vb01 = *reinterpret_cast<const short8*>(vp + 512);
    short8 vb10 = *reinterpret_cast<const short8*>(vp + 1024);
    short8 vb11 = *reinterpret_cast<const short8*>(vp + 1536);

    for (int it = 0; it < 16; ++it) {
        short8 ck0 = k0, ck1 = k1, ck2 = k2, ck3 = k3;
        short8 cv00 = vb00, cv01 = vb01, cv10 = vb10, cv11 = vb11;
        // issue next iteration's global loads now; their latency hides under
        // QK + exp/pack + PV of the current iteration
        if (it + 1 < 16) {
            kp += 2048; vp += 2048;
            k0 = *reinterpret_cast<const short8*>(kp);
            k1 = *reinterpret_cast<const short8*>(kp + 512);
            k2 = *reinterpret_cast<const short8*>(kp + 1024);
            k3 = *reinterpret_cast<const short8*>(kp + 1536);
            vb00 = *reinterpret_cast<const short8*>(vp);
            vb01 = *reinterpret_cast<const short8*>(vp + 512);
            vb10 = *reinterpret_cast<const short8*>(vp + 1024);
            vb11 = *reinterpret_cast<const short8*>(vp + 1536);
        }
        // S^T = K Q^T: lane (quad,l16) gets S[q=l16][key=c*16+quad*4+r] in s_c[r]
        floatx4 z = {};
        floatx4 s0 = __builtin_amdgcn_mfma_f32_16x16x32_bf16(ck0, aq, z, 0, 0, 0);
        floatx4 s1 = __builtin_amdgcn_mfma_f32_16x16x32_bf16(ck1, aq, z, 0, 0, 0);
        floatx4 s2 = __builtin_amdgcn_mfma_f32_16x16x32_bf16(ck2, aq, z, 0, 0, 0);
        floatx4 s3 = __builtin_amdgcn_mfma_f32_16x16x32_bf16(ck3, aq, z, 0, 0, 0);
        // exp (no max subtraction: |s|≲8 with LN'd inputs); pack in-register into
        // the two PV A-fragments (pos permutation matches vt tiles)
        float p00 = __expf(s0[0]), p01 = __expf(s0[1]), p02 = __expf(s0[2]), p03 = __expf(s0[3]);
        float p10 = __expf(s1[0]), p11 = __expf(s1[1]), p12 = __expf(s1[2]), p13 = __expf(s1[3]);
        float p20 = __expf(s2[0]), p21 = __expf(s2[1]), p22 = __expf(s2[2]), p23 = __expf(s2[3]);
        float p30 = __expf(s3[0]), p31 = __expf(s3[1]), p32 = __expf(s3[2]), p33 = __expf(s3[3]);
        lsum += ((p00 + p01) + (p02 + p03)) + ((p10 + p11) + (p12 + p13))
              + ((p20 + p21) + (p22 + p23)) + ((p30 + p31) + (p32 + p33));
        uint4 ua, ub;
        ua.x = pk2(p00, p01); ua.y = pk2(p02, p03); ua.z = pk2(p10, p11); ua.w = pk2(p12, p13);
        ub.x = pk2(p20, p21); ub.y = pk2(p22, p23); ub.z = pk2(p30, p31); ub.w = pk2(p32, p33);
        short8 pa0 = __builtin_bit_cast(short8, ua);
        short8 pa1 = __builtin_bit_cast(short8, ub);
        // O += P V entirely from registers
        o0 = __builtin_amdgcn_mfma_f32_16x16x32_bf16(pa0, cv00, o0, 0, 0, 0);
        o0 = __builtin_amdgcn_mfma_f32_16x16x32_bf16(pa1, cv01, o0, 0, 0, 0);
        o1 = __builtin_amdgcn_mfma_f32_16x16x32_bf16(pa0, cv10, o1, 0, 0, 0);
        o1 = __builtin_amdgcn_mfma_f32_16x16x32_bf16(pa1, cv11, o1, 0, 0, 0);
    }
    // denom for query l16: sum the 4 quads' partials (lanes l16, l16+16, l16+32, l16+48)
    lsum += __shfl_xor(lsum, 16);
    lsum += __shfl_xor(lsum, 32);
    #pragma unroll
    for (int r = 0; r < 4; ++r) {
        float inv = 1.0f / __shfl(lsum, quad * 4 + r);
        int q = qti * 64 + wave * 16 + quad * 4 + r;
        int t = tb + tok_of(br, wb, q);
        size_t o = (((size_t)(t >> 4) * 6 + (coff >> 5)) << 9) + ((t & 15) << 5);
        attb[o + l16]      = f2b(o0[r] * inv);
        attb[o + 16 + l16] = f2b(o1[r] * inv);
    }
}

// ---------------- LN over rows of (B*L, 192): f32 in -> bf16 out (fragment-packed) --------
__global__ __launch_bounds__(256) void ln_kernel(const float* __restrict__ in,
        const float* __restrict__ g, const float* __restrict__ bb, unsigned short* __restrict__ out) {
    int token = (blockIdx.x << 2) + (threadIdx.x >> 6);
    int lane = threadIdx.x & 63;
    const float* row = in + (size_t)token * 192;
    float v0 = row[lane], v1 = row[lane + 64], v2 = row[lane + 128];
    float s = v0 + v1 + v2, sq = v0 * v0 + v1 * v1 + v2 * v2;
    #pragma unroll
    for (int mask = 1; mask < 64; mask <<= 1) {
        s += __shfl_xor(s, mask);
        sq += __shfl_xor(sq, mask);
    }
    float m = s * (1.f / 192.f);
    float var = sq * (1.f / 192.f) - m * m;
    float rsd = rsqrtf(var + 1e-5f);
    int tbase = (token >> 4) * 6, tr = (token & 15) << 5;
    int lo = lane >> 5, la = lane & 31;
    out[((tbase + lo)     << 9) + tr + la] = f2b((v0 - m) * rsd * g[lane]       + bb[lane]);
    out[((tbase + lo + 2) << 9) + tr + la] = f2b((v1 - m) * rsd * g[lane + 64]  + bb[lane + 64]);
    out[((tbase + lo + 4) << 9) + tr + la] = f2b((v2 - m) * rsd * g[lane + 128] + bb[lane + 128]);
}

// ---------------- final transpose (B*L,C) f32 -> (B,C,4096) out dtype per flag ----------------
__global__ __launch_bounds__(256) void unprep_kernel(const float* __restrict__ xs,
                                                     void* __restrict__ out,
                                                     const int* __restrict__ flag) {
    __shared__ float tile[192][33];
    int tid = threadIdx.x;
    int t0 = blockIdx.x * 32;
    int b = t0 >> 12, ts = t0 & 4095;
    for (int idx = tid; idx < 32 * 192; idx += 256) {
        int tt = idx / 192, c = idx % 192;
        tile[c][tt] = xs[(size_t)(t0 + tt) * 192 + c];
    }
    __syncthreads();
    int f = *flag;
    for (int idx = tid; idx < 192 * 32; idx += 256) {
        int c = idx >> 5, tt = idx & 31;
        float v = tile[c][tt];
        int o = ((b * 192 + c) << 12) + ts + tt;
        if (f) ((float*)out)[o] = v;
        else   ((unsigned short*)out)[o] = f2b(v);
    }
}

extern "C" void kernel_launch(void* const* d_in, const int* in_sizes, int n_in,
                              void* d_out, int out_size, void* d_ws, size_t ws_size,
                              hipStream_t stream) {
    float* ws = (float*)d_ws;

    // small fp32 vectors: b_proj, g1, b1, g2, b2, b_fc1, b_fc2 (1920 floats)
    float* vbase = ws;
    float* bprojf = vbase + 0;
    float* g1f    = vbase + 192;
    float* b1f    = vbase + 384;
    float* g2f    = vbase + 576;
    float* b2f    = vbase + 768;
    float* bfc1f  = vbase + 960;
    float* bfc2f  = vbase + 1728;

    // fragment-packed bf16 weights, 442368 ushorts
    unsigned short* wbase = (unsigned short*)(ws + 1920);
    unsigned short* wqkvT = wbase + 0;
    unsigned short* wprojT = wbase + 110592;
    unsigned short* wfc1T = wbase + 147456;
    unsigned short* wfc2T = wbase + 294912;

    size_t p = 1920 + 442368 / 2;           // float offset after weights
    float* xt = ws + p; p += SZ;            // fp32 residual stream (xs)
    unsigned short* img = (unsigned short*)(ws + p); p += SZ / 2;   // bf16 packed; also lnb
    size_t pQ = p;
    unsigned short* hbuf = (unsigned short*)(ws + pQ);              // bf16 packed 8192x768
    p = pQ + 8192 * 768 / 2;
    unsigned short* attb = (unsigned short*)(ws + p); p += SZ / 2;  // bf16 packed
    int* flag = (int*)(ws + p); p += 16;
    // packed Q tiles: [b][brh=6][wb=4][qchunk=64][16x32] bf16 (3MB)
    unsigned short* qtb = (unsigned short*)(ws + p); p += SZ / 2;
    // packed K tiles: [b][brh=6][wb=4][chunk=16][ctile=4][16x32] bf16 (3MB)
    unsigned short* ktb = (unsigned short*)(ws + p); p += SZ / 2;
    // packed V tiles: [b][brh=6][wb=4][chunk=16][tidx=4][16x32] bf16 (3MB)
    unsigned short* vtb = (unsigned short*)(ws + p); p += SZ / 2;
    float* xs = xt;
    unsigned short* lnb = img;

    WPA wa;
    wa.s[0] = d_in[1];  wa.s[1] = d_in[2];  wa.s[2] = d_in[8];  wa.s[3] = d_in[10];
    wa.s[4] = d_in[3];  wa.s[5] = d_in[4];  wa.s[6] = d_in[5];  wa.s[7] = d_in[6];
    wa.s[8] = d_in[7];  wa.s[9] = d_in[9];  wa.s[10] = d_in[11];

    detect_kernel<<<dim3(1), dim3(256), 0, stream>>>((const unsigned short*)d_in[0], flag);
    wprep_kernel<<<dim3(1736), dim3(256), 0, stream>>>(wa, wbase, vbase, flag);
    prep_kernel<<<dim3(256), dim3(256), 0, stream>>>(d_in[0], flag, g1f, b1f, xt, img);
    // qkv: 2-wave blocks (1152 blocks); Q/K/V all go into packed tile buffers
    mfma_gemm<0, 2><<<dim3(128, 9), dim3(128), 0, stream>>>(
        img, wqkvT, nullptr, nullptr, nullptr, qtb, ktb, vtb, 576, 192);
    // attention: single-pass, 768 blocks, fully coalesced packed loads
    attn_mfma<<<dim3(768), dim3(256), 0, stream>>>(qtb, ktb, vtb, attb);
    // proj: 1-wave blocks (768 blocks, 3/CU — every CU busy)
    mfma_gemm<1, 1><<<dim3(256, 3), dim3(64), 0, stream>>>(
        attb, wprojT, bprojf, xt, xs, nullptr, nullptr, nullptr, 192, 192);
    ln_kernel<<<dim3(2048), dim3(256), 0, stream>>>(xs, g2f, b2f, lnb);
    // fc1: 2-wave blocks (1536 blocks, 6/CU)
    mfma_gemm<2, 2><<<dim3(128, 12), dim3(128), 0, stream>>>(
        lnb, wfc1T, bfc1f, nullptr, hbuf, nullptr, nullptr, nullptr, 768, 192);
    // fc2: 1-wave blocks (768 blocks, 3/CU)
    mfma_gemm<3, 1><<<dim3(256, 3), dim3(64), 0, stream>>>(
        hbuf, wfc2T, bfc2f, xs, xs, nullptr, nullptr, nullptr, 192, 768);
    unprep_kernel<<<dim3(256), dim3(256), 0, stream>>>(xs, d_out, flag);
}